// Round 2
// baseline (10758.967 us; speedup 1.0000x reference)
//
#include <hip/hip_runtime.h>

// ---------------- problem constants (match reference) ----------------
constexpr int N_NEWS = 50000, N_KW = 10000, N_ST = 2000;
constexpr int F_NEWS = 768, F_KW = 128, F_ST = 64;
constexpr int HID = 256, OUTD = 128;
constexpr int E_HK = 500000, E_HS = 250000, E_LBL = 150000;

// ---------------- generic fp32 GEMM: C = [C] + A'[M,K] @ W[N,K]^T [+ bias] [relu]
#define BM 128
#define BN 128
#define BK 16
#define PADF 4

enum { FLAG_ACC = 1, FLAG_RELU = 2 };

__global__ __launch_bounds__(256) void gemm_kernel(
    const float* __restrict__ A, const int* __restrict__ rowidx, int lda,
    const float* __restrict__ W, int ldw,
    const float* __restrict__ bias,
    float* __restrict__ C, int ldc,
    int M, int N, int K, int flags)
{
    __shared__ float As[BK][BM + PADF];
    __shared__ float Bs[BK][BN + PADF];
    const int tid = threadIdx.x;
    const int bm = blockIdx.x * BM;
    const int bn = blockIdx.y * BN;
    const int tx = tid & 15;
    const int ty = tid >> 4;

    const int lrow = tid >> 2;          // 0..63
    const int lcol = (tid & 3) << 2;    // 0,4,8,12

    const float* Ar0 = nullptr; const float* Ar1 = nullptr;
    {
        int r0 = bm + lrow, r1 = bm + lrow + 64;
        if (r0 < M) Ar0 = A + (size_t)(rowidx ? rowidx[r0] : r0) * lda;
        if (r1 < M) Ar1 = A + (size_t)(rowidx ? rowidx[r1] : r1) * lda;
    }
    const float* Wr0 = nullptr; const float* Wr1 = nullptr;
    {
        int n0 = bn + lrow, n1 = bn + lrow + 64;
        if (n0 < N) Wr0 = W + (size_t)n0 * ldw;
        if (n1 < N) Wr1 = W + (size_t)n1 * ldw;
    }

    float acc[8][8];
    #pragma unroll
    for (int i = 0; i < 8; ++i)
        #pragma unroll
        for (int j = 0; j < 8; ++j) acc[i][j] = 0.f;

    for (int k0 = 0; k0 < K; k0 += BK) {
        float4 a0 = {0,0,0,0}, a1 = {0,0,0,0}, w0 = {0,0,0,0}, w1 = {0,0,0,0};
        if (Ar0) a0 = *(const float4*)(Ar0 + k0 + lcol);
        if (Ar1) a1 = *(const float4*)(Ar1 + k0 + lcol);
        if (Wr0) w0 = *(const float4*)(Wr0 + k0 + lcol);
        if (Wr1) w1 = *(const float4*)(Wr1 + k0 + lcol);
        __syncthreads();
        As[lcol+0][lrow]    = a0.x; As[lcol+1][lrow]    = a0.y; As[lcol+2][lrow]    = a0.z; As[lcol+3][lrow]    = a0.w;
        As[lcol+0][lrow+64] = a1.x; As[lcol+1][lrow+64] = a1.y; As[lcol+2][lrow+64] = a1.z; As[lcol+3][lrow+64] = a1.w;
        Bs[lcol+0][lrow]    = w0.x; Bs[lcol+1][lrow]    = w0.y; Bs[lcol+2][lrow]    = w0.z; Bs[lcol+3][lrow]    = w0.w;
        Bs[lcol+0][lrow+64] = w1.x; Bs[lcol+1][lrow+64] = w1.y; Bs[lcol+2][lrow+64] = w1.z; Bs[lcol+3][lrow+64] = w1.w;
        __syncthreads();
        #pragma unroll
        for (int k = 0; k < BK; ++k) {
            float a[8], b[8];
            *(float4*)&a[0] = *(const float4*)&As[k][ty * 8];
            *(float4*)&a[4] = *(const float4*)&As[k][ty * 8 + 4];
            *(float4*)&b[0] = *(const float4*)&Bs[k][tx * 8];
            *(float4*)&b[4] = *(const float4*)&Bs[k][tx * 8 + 4];
            #pragma unroll
            for (int i = 0; i < 8; ++i)
                #pragma unroll
                for (int j = 0; j < 8; ++j)
                    acc[i][j] = fmaf(a[i], b[j], acc[i][j]);
        }
    }

    #pragma unroll
    for (int i = 0; i < 8; ++i) {
        int row = bm + ty * 8 + i;
        if (row >= M) continue;
        float* Crow = C + (size_t)row * ldc;
        #pragma unroll
        for (int j = 0; j < 8; ++j) {
            int col = bn + tx * 8 + j;
            if (col >= N) continue;
            float v = acc[i][j];
            if (flags & FLAG_ACC) v += Crow[col];
            if (bias) v += bias[col];
            if (flags & FLAG_RELU) v = fmaxf(v, 0.f);
            Crow[col] = v;
        }
    }
}

// ---------------- aggregate-first scatter (D=256) + divide ----------------
__global__ void scatter_kernel(const float* __restrict__ X,
                               const int* __restrict__ srcidx,
                               const int* __restrict__ dstidx,
                               float* __restrict__ S, float* __restrict__ cnt,
                               int E)
{
    int t = blockIdx.x * blockDim.x + threadIdx.x;
    if (t >= E * 64) return;
    int e  = t >> 6;
    int c4 = (t & 63) << 2;
    int s = srcidx[e], d = dstidx[e];
    float4 v = *(const float4*)(X + (size_t)s * 256 + c4);
    float* o = S + (size_t)d * 256 + c4;
    atomicAdd(o + 0, v.x);
    atomicAdd(o + 1, v.y);
    atomicAdd(o + 2, v.z);
    atomicAdd(o + 3, v.w);
    if (c4 == 0) atomicAdd(cnt + d, 1.0f);
}

__global__ void seg_div_kernel(float* __restrict__ S, const float* __restrict__ cnt, int n)
{
    int t = blockIdx.x * blockDim.x + threadIdx.x;
    if (t >= n * 64) return;
    int r = t >> 6;
    float inv = 1.0f / fmaxf(cnt[r], 1.0f);
    float4* p = (float4*)(S + ((size_t)t << 2));
    float4 v = *p;
    v.x *= inv; v.y *= inv; v.z *= inv; v.w *= inv;
    *p = v;
}

// ---------------- project-first scaled scatter: Out[dst] += X[src] * inv[dst] ----------------
template <int D>
__global__ void scatter_scaled_kernel(const float* __restrict__ X,
                                      const int* __restrict__ srcidx,
                                      const int* __restrict__ dstidx,
                                      const float* __restrict__ inv,
                                      float* __restrict__ Out, int E)
{
    constexpr int TPE = D / 4;
    int t = blockIdx.x * blockDim.x + threadIdx.x;
    if (t >= E * TPE) return;
    int e  = t / TPE;
    int c4 = (t % TPE) * 4;
    int s = srcidx[e], d = dstidx[e];
    float sc = inv[d];
    float4 v = *(const float4*)(X + (size_t)s * D + c4);
    float* o = Out + (size_t)d * D + c4;
    atomicAdd(o + 0, v.x * sc);
    atomicAdd(o + 1, v.y * sc);
    atomicAdd(o + 2, v.z * sc);
    atomicAdd(o + 3, v.w * sc);
}

// ---------------- degree helpers ----------------
__global__ void count_kernel(const int* __restrict__ idx, float* __restrict__ deg, int E)
{
    int e = blockIdx.x * blockDim.x + threadIdx.x;
    if (e < E) atomicAdd(deg + idx[e], 1.0f);
}

__global__ void invert_kernel(float* __restrict__ deg, int n)
{
    int i = blockIdx.x * blockDim.x + threadIdx.x;
    if (i < n) deg[i] = 1.0f / fmaxf(deg[i], 1.0f);
}

__global__ void add2_kernel(const float* __restrict__ a, const float* __restrict__ b,
                            float* __restrict__ o, int n)
{
    int i = blockIdx.x * blockDim.x + threadIdx.x;
    if (i < n) o[i] = a[i] + b[i];
}

// ---------------- final decoder dot ----------------
__global__ void dot_kernel(const float* __restrict__ H, const float* __restrict__ w,
                           const float* __restrict__ db, float* __restrict__ out, int E)
{
    int e = blockIdx.x * blockDim.x + threadIdx.x;
    if (e >= E) return;
    const float4* h = (const float4*)(H + (size_t)e * 128);
    const float4* wv = (const float4*)w;
    float s = 0.f;
    #pragma unroll
    for (int i = 0; i < 32; ++i) {
        float4 a = h[i], b = wv[i];
        s += a.x * b.x + a.y * b.y + a.z * b.z + a.w * b.w;
    }
    out[e] = s + db[0];
}

// ---------------- launch ----------------
extern "C" void kernel_launch(void* const* d_in, const int* in_sizes, int n_in,
                              void* d_out, int out_size, void* d_ws, size_t ws_size,
                              hipStream_t stream)
{
    const float* x_news = (const float*)d_in[0];
    const float* x_kw   = (const float*)d_in[1];
    const float* x_st   = (const float*)d_in[2];
    const float* Wn = (const float*)d_in[3];  const float* bn = (const float*)d_in[4];
    const float* Wk = (const float*)d_in[5];  const float* bk = (const float*)d_in[6];
    const float* Wst = (const float*)d_in[7]; const float* bs = (const float*)d_in[8];
    const float* W1l = (const float*)d_in[9];  const float* b1 = (const float*)d_in[10];
    const float* W1r = (const float*)d_in[11];
    const float* W2l = (const float*)d_in[12]; const float* b2 = (const float*)d_in[13];
    const float* W2r = (const float*)d_in[14];
    const float* DW1 = (const float*)d_in[15]; const float* Db1 = (const float*)d_in[16];
    const float* DW2 = (const float*)d_in[17]; const float* Db2 = (const float*)d_in[18];
    const int* e_hk_src = (const int*)d_in[19];
    const int* e_hk_dst = (const int*)d_in[20];
    const int* e_hs_src = (const int*)d_in[21];
    const int* e_hs_dst = (const int*)d_in[22];
    const int* l_hk_src = (const int*)d_in[23];
    const int* l_hk_dst = (const int*)d_in[24];
    const int* l_hs_src = (const int*)d_in[25];
    const int* l_hs_dst = (const int*)d_in[26];
    float* out = (float*)d_out;

    // ---- workspace layout (floats), total ~34.52M floats = 138.1 MB ----
    float* ws = (float*)d_ws;
    size_t o = 0;
    float* HN  = ws + o; o += (size_t)N_NEWS * HID;   // 12.80M
    float* HK  = ws + o; o += (size_t)N_KW * HID;     //  2.56M
    float* HS  = ws + o; o += (size_t)N_ST * HID;     //  0.512M
    float* K1  = ws + o; o += (size_t)N_KW * HID;     //  2.56M
    float* S1  = ws + o; o += (size_t)N_ST * HID;     //  0.512M
    float* P   = ws + o; o += (size_t)N_KW * HID;     //  2.56M  (max agg/proj scratch)
    float* N1  = ws + o; o += (size_t)N_NEWS * HID;   // 12.80M
    float* DEGa = ws + o; o += 50048;                 // 1/deg(news) over e_hk
    float* DEGb = ws + o; o += 50048;                 // 1/deg(news) over e_hs
    float* CNT  = ws + o; o += 10048;                 // agg count (max N_KW)
    float* WS1s = ws + o; o += 65536;                 // W1r[1]+W1r[3]
    float* WS2s = ws + o; o += 32768;                 // W2r[1]+W2r[3]
    float* BS1  = ws + o; o += 256;
    float* BS2  = ws + o; o += 128;

    // overlays: layer-2 outputs reuse HN (dead after layer 1)
    float* K2 = HN;                                   // 10000x128 = 1.28M
    float* N2 = HN + (size_t)N_KW * OUTD;             // 50000x128 = 6.40M
    float* S2 = N2 + (size_t)N_NEWS * OUTD;           //  2000x128 = 0.256M (7.94M <= 12.8M)
    // decoder hidden reuses HK..N1 (dead after layer 2): 19.2M <= 21.5M
    float* HB = HK;

    auto gemm = [&](const float* A, const int* ridx, int lda, const float* W, int ldw,
                    const float* bias, float* C, int ldc, int M, int N, int K, int flags) {
        dim3 g((M + BM - 1) / BM, (N + BN - 1) / BN);
        gemm_kernel<<<g, dim3(256), 0, stream>>>(A, ridx, lda, W, ldw, bias, C, ldc, M, N, K, flags);
    };
    auto agg256 = [&](const float* X, const int* sidx, const int* didx, int E, int ndst) {
        hipMemsetAsync(P, 0, (size_t)ndst * HID * sizeof(float), stream);
        hipMemsetAsync(CNT, 0, (size_t)ndst * sizeof(float), stream);
        scatter_kernel<<<(E * 64 + 255) / 256, 256, 0, stream>>>(X, sidx, didx, P, CNT, E);
        seg_div_kernel<<<(ndst * 64 + 255) / 256, 256, 0, stream>>>(P, CNT, ndst);
    };

    // ---- degrees (1/deg for project-first relations) + summed weights ----
    hipMemsetAsync(DEGa, 0, N_NEWS * sizeof(float), stream);
    hipMemsetAsync(DEGb, 0, N_NEWS * sizeof(float), stream);
    count_kernel<<<(E_HK + 255) / 256, 256, 0, stream>>>(e_hk_src, DEGa, E_HK);
    count_kernel<<<(E_HS + 255) / 256, 256, 0, stream>>>(e_hs_src, DEGb, E_HS);
    invert_kernel<<<(N_NEWS + 255) / 256, 256, 0, stream>>>(DEGa, N_NEWS);
    invert_kernel<<<(N_NEWS + 255) / 256, 256, 0, stream>>>(DEGb, N_NEWS);

    const size_t WS1 = (size_t)HID * HID;   // 65536
    const size_t WS2 = (size_t)OUTD * HID;  // 32768
    add2_kernel<<<(65536 + 255) / 256, 256, 0, stream>>>(W1r + 1 * WS1, W1r + 3 * WS1, WS1s, 65536);
    add2_kernel<<<(32768 + 255) / 256, 256, 0, stream>>>(W2r + 1 * WS2, W2r + 3 * WS2, WS2s, 32768);
    add2_kernel<<<1, 256, 0, stream>>>(b1 + 1 * HID, b1 + 3 * HID, BS1, 256);
    add2_kernel<<<1, 128, 0, stream>>>(b2 + 1 * OUTD, b2 + 3 * OUTD, BS2, 128);

    // ---- input projections ----
    gemm(x_news, nullptr, F_NEWS, Wn,  F_NEWS, bn, HN, HID, N_NEWS, HID, F_NEWS, FLAG_RELU);
    gemm(x_kw,   nullptr, F_KW,   Wk,  F_KW,   bk, HK, HID, N_KW,   HID, F_KW,   FLAG_RELU);
    gemm(x_st,   nullptr, F_ST,   Wst, F_ST,   bs, HS, HID, N_ST,   HID, F_ST,   FLAG_RELU);

    // ---- layer 1 ----
    // k1 = relu(mean_hk(hn)@W1l0^T + b1[0] + hk@W1r0^T)   [aggregate-first]
    agg256(HN, e_hk_src, e_hk_dst, E_HK, N_KW);
    gemm(P,  nullptr, HID, W1l + 0 * WS1, HID, b1 + 0 * HID, K1, HID, N_KW, HID, HID, 0);
    gemm(HK, nullptr, HID, W1r + 0 * WS1, HID, nullptr,      K1, HID, N_KW, HID, HID, FLAG_ACC | FLAG_RELU);
    // s1   [aggregate-first]
    agg256(HN, e_hs_src, e_hs_dst, E_HS, N_ST);
    gemm(P,  nullptr, HID, W1l + 2 * WS1, HID, b1 + 2 * HID, S1, HID, N_ST, HID, HID, 0);
    gemm(HS, nullptr, HID, W1r + 2 * WS1, HID, nullptr,      S1, HID, N_ST, HID, HID, FLAG_ACC | FLAG_RELU);
    // n1   [project-first: scatter projected kw/st into N1, then fused r-term]
    hipMemsetAsync(N1, 0, (size_t)N_NEWS * HID * sizeof(float), stream);
    gemm(HK, nullptr, HID, W1l + 1 * WS1, HID, nullptr, P, HID, N_KW, HID, HID, 0);
    scatter_scaled_kernel<256><<<(E_HK * 64 + 255) / 256, 256, 0, stream>>>(P, e_hk_dst, e_hk_src, DEGa, N1, E_HK);
    gemm(HS, nullptr, HID, W1l + 3 * WS1, HID, nullptr, P, HID, N_ST, HID, HID, 0);
    scatter_scaled_kernel<256><<<(E_HS * 64 + 255) / 256, 256, 0, stream>>>(P, e_hs_dst, e_hs_src, DEGb, N1, E_HS);
    gemm(HN, nullptr, HID, WS1s, HID, BS1, N1, HID, N_NEWS, HID, HID, FLAG_ACC | FLAG_RELU);

    // ---- layer 2 (no relu) ----
    // k2   [aggregate-first]
    agg256(N1, e_hk_src, e_hk_dst, E_HK, N_KW);
    gemm(P,  nullptr, HID, W2l + 0 * WS2, HID, b2 + 0 * OUTD, K2, OUTD, N_KW, OUTD, HID, 0);
    gemm(K1, nullptr, HID, W2r + 0 * WS2, HID, nullptr,       K2, OUTD, N_KW, OUTD, HID, FLAG_ACC);
    // s2   [aggregate-first]
    agg256(N1, e_hs_src, e_hs_dst, E_HS, N_ST);
    gemm(P,  nullptr, HID, W2l + 2 * WS2, HID, b2 + 2 * OUTD, S2, OUTD, N_ST, OUTD, HID, 0);
    gemm(S1, nullptr, HID, W2r + 2 * WS2, HID, nullptr,       S2, OUTD, N_ST, OUTD, HID, FLAG_ACC);
    // n2   [project-first]
    hipMemsetAsync(N2, 0, (size_t)N_NEWS * OUTD * sizeof(float), stream);
    gemm(K1, nullptr, HID, W2l + 1 * WS2, HID, nullptr, P, OUTD, N_KW, OUTD, HID, 0);
    scatter_scaled_kernel<128><<<(E_HK * 32 + 255) / 256, 256, 0, stream>>>(P, e_hk_dst, e_hk_src, DEGa, N2, E_HK);
    gemm(S1, nullptr, HID, W2l + 3 * WS2, HID, nullptr, P, OUTD, N_ST, OUTD, HID, 0);
    scatter_scaled_kernel<128><<<(E_HS * 32 + 255) / 256, 256, 0, stream>>>(P, e_hs_dst, e_hs_src, DEGb, N2, E_HS);
    gemm(N1, nullptr, HID, WS2s, HID, BS2, N2, OUTD, N_NEWS, OUTD, HID, FLAG_ACC);

    // ---- decoders ----
    const size_t DWS = (size_t)OUTD * (2 * OUTD); // 32768
    // has_keyword
    gemm(N2, l_hk_src, OUTD, DW1 + 0 * DWS,        2 * OUTD, Db1 + 0 * OUTD, HB, OUTD, E_LBL, OUTD, OUTD, 0);
    gemm(K2, l_hk_dst, OUTD, DW1 + 0 * DWS + OUTD, 2 * OUTD, nullptr,        HB, OUTD, E_LBL, OUTD, OUTD, FLAG_ACC | FLAG_RELU);
    dot_kernel<<<(E_LBL + 255) / 256, 256, 0, stream>>>(HB, DW2 + 0 * OUTD, Db2 + 0, out, E_LBL);
    // has_stock
    gemm(N2, l_hs_src, OUTD, DW1 + 1 * DWS,        2 * OUTD, Db1 + 1 * OUTD, HB, OUTD, E_LBL, OUTD, OUTD, 0);
    gemm(S2, l_hs_dst, OUTD, DW1 + 1 * DWS + OUTD, 2 * OUTD, nullptr,        HB, OUTD, E_LBL, OUTD, OUTD, FLAG_ACC | FLAG_RELU);
    dot_kernel<<<(E_LBL + 255) / 256, 256, 0, stream>>>(HB, DW2 + 1 * OUTD, Db2 + 1, out + E_LBL, E_LBL);
}

// Round 3
// 2417.074 us; speedup vs baseline: 4.4512x; 4.4512x over previous
//
#include <hip/hip_runtime.h>

// ---------------- problem constants (match reference) ----------------
constexpr int N_NEWS = 50000, N_KW = 10000, N_ST = 2000;
constexpr int F_NEWS = 768, F_KW = 128, F_ST = 64;
constexpr int HID = 256, OUTD = 128;
constexpr int E_HK = 500000, E_HS = 250000, E_LBL = 150000;

// ---------------- generic fp32 GEMM: C = [C] + A'[M,K] @ W[N,K]^T [+ bias] [relu]
#define BM 128
#define BN 128
#define BK 16
#define PADF 4

enum { FLAG_ACC = 1, FLAG_RELU = 2 };

__global__ __launch_bounds__(256) void gemm_kernel(
    const float* __restrict__ A, const int* __restrict__ rowidx, int lda,
    const float* __restrict__ W, int ldw,
    const float* __restrict__ bias,
    float* __restrict__ C, int ldc,
    int M, int N, int K, int flags)
{
    __shared__ float As[BK][BM + PADF];
    __shared__ float Bs[BK][BN + PADF];
    const int tid = threadIdx.x;
    const int bm = blockIdx.x * BM;
    const int bn = blockIdx.y * BN;
    const int tx = tid & 15;
    const int ty = tid >> 4;

    const int lrow = tid >> 2;          // 0..63
    const int lcol = (tid & 3) << 2;    // 0,4,8,12

    const float* Ar0 = nullptr; const float* Ar1 = nullptr;
    {
        int r0 = bm + lrow, r1 = bm + lrow + 64;
        if (r0 < M) Ar0 = A + (size_t)(rowidx ? rowidx[r0] : r0) * lda;
        if (r1 < M) Ar1 = A + (size_t)(rowidx ? rowidx[r1] : r1) * lda;
    }
    const float* Wr0 = nullptr; const float* Wr1 = nullptr;
    {
        int n0 = bn + lrow, n1 = bn + lrow + 64;
        if (n0 < N) Wr0 = W + (size_t)n0 * ldw;
        if (n1 < N) Wr1 = W + (size_t)n1 * ldw;
    }

    float acc[8][8];
    #pragma unroll
    for (int i = 0; i < 8; ++i)
        #pragma unroll
        for (int j = 0; j < 8; ++j) acc[i][j] = 0.f;

    for (int k0 = 0; k0 < K; k0 += BK) {
        float4 a0 = {0,0,0,0}, a1 = {0,0,0,0}, w0 = {0,0,0,0}, w1 = {0,0,0,0};
        if (Ar0) a0 = *(const float4*)(Ar0 + k0 + lcol);
        if (Ar1) a1 = *(const float4*)(Ar1 + k0 + lcol);
        if (Wr0) w0 = *(const float4*)(Wr0 + k0 + lcol);
        if (Wr1) w1 = *(const float4*)(Wr1 + k0 + lcol);
        __syncthreads();
        As[lcol+0][lrow]    = a0.x; As[lcol+1][lrow]    = a0.y; As[lcol+2][lrow]    = a0.z; As[lcol+3][lrow]    = a0.w;
        As[lcol+0][lrow+64] = a1.x; As[lcol+1][lrow+64] = a1.y; As[lcol+2][lrow+64] = a1.z; As[lcol+3][lrow+64] = a1.w;
        Bs[lcol+0][lrow]    = w0.x; Bs[lcol+1][lrow]    = w0.y; Bs[lcol+2][lrow]    = w0.z; Bs[lcol+3][lrow]    = w0.w;
        Bs[lcol+0][lrow+64] = w1.x; Bs[lcol+1][lrow+64] = w1.y; Bs[lcol+2][lrow+64] = w1.z; Bs[lcol+3][lrow+64] = w1.w;
        __syncthreads();
        #pragma unroll
        for (int k = 0; k < BK; ++k) {
            float a[8], b[8];
            *(float4*)&a[0] = *(const float4*)&As[k][ty * 8];
            *(float4*)&a[4] = *(const float4*)&As[k][ty * 8 + 4];
            *(float4*)&b[0] = *(const float4*)&Bs[k][tx * 8];
            *(float4*)&b[4] = *(const float4*)&Bs[k][tx * 8 + 4];
            #pragma unroll
            for (int i = 0; i < 8; ++i)
                #pragma unroll
                for (int j = 0; j < 8; ++j)
                    acc[i][j] = fmaf(a[i], b[j], acc[i][j]);
        }
    }

    #pragma unroll
    for (int i = 0; i < 8; ++i) {
        int row = bm + ty * 8 + i;
        if (row >= M) continue;
        float* Crow = C + (size_t)row * ldc;
        #pragma unroll
        for (int j = 0; j < 8; ++j) {
            int col = bn + tx * 8 + j;
            if (col >= N) continue;
            float v = acc[i][j];
            if (flags & FLAG_ACC) v += Crow[col];
            if (bias) v += bias[col];
            if (flags & FLAG_RELU) v = fmaxf(v, 0.f);
            Crow[col] = v;
        }
    }
}

// ---------------- CSR build ----------------
__global__ void count_kernel(const int* __restrict__ key, int* __restrict__ deg, int E)
{
    int e = blockIdx.x * blockDim.x + threadIdx.x;
    if (e < E) atomicAdd(deg + key[e], 1);
}

// exclusive scan, two-level (n <= 256*256)
__global__ void scan_block_kernel(const int* __restrict__ in, int* __restrict__ out,
                                  int* __restrict__ bsum, int n)
{
    __shared__ int tmp[256];
    int i = blockIdx.x * 256 + threadIdx.x;
    int v = (i < n) ? in[i] : 0;
    tmp[threadIdx.x] = v;
    __syncthreads();
    #pragma unroll
    for (int off = 1; off < 256; off <<= 1) {
        int t = (threadIdx.x >= off) ? tmp[threadIdx.x - off] : 0;
        __syncthreads();
        tmp[threadIdx.x] += t;
        __syncthreads();
    }
    if (i < n) out[i] = tmp[threadIdx.x] - v;   // exclusive within block
    if (threadIdx.x == 255 && bsum) bsum[blockIdx.x] = tmp[255];
}

__global__ void scan_add_kernel(int* __restrict__ out, const int* __restrict__ bsumex, int n)
{
    int i = blockIdx.x * 256 + threadIdx.x;
    if (i < n) out[i] += bsumex[blockIdx.x];
}

// cursor holds exclusive-scan ptr; after fill, cursor[r] == row_end(r)
__global__ void csr_fill_kernel(const int* __restrict__ key, const int* __restrict__ val,
                                int* __restrict__ cursor, int* __restrict__ adj, int E)
{
    int e = blockIdx.x * blockDim.x + threadIdx.x;
    if (e < E) {
        int p = atomicAdd(cursor + key[e], 1);
        adj[p] = val[e];
    }
}

// ---------------- gather mean: Out[r] (=/+=) mean_{s in adj[r]} X[s] ----------------
template <int D, bool ACC>
__global__ void gather_mean_kernel(const float* __restrict__ X,
                                   const int* __restrict__ cursor,  // post-fill: cursor[r] = end(r)
                                   const int* __restrict__ adj,
                                   float* __restrict__ Out, int ndst)
{
    constexpr int LANES = D / 4;          // threads per row
    constexpr int RPB = 256 / LANES;      // rows per block
    int r = blockIdx.x * RPB + threadIdx.x / LANES;
    if (r >= ndst) return;
    int lane = threadIdx.x % LANES;
    int beg = (r == 0) ? 0 : cursor[r - 1];
    int end = cursor[r];
    float4 s = {0.f, 0.f, 0.f, 0.f};
    int j = beg;
    for (; j + 1 < end; j += 2) {
        int s0 = adj[j], s1 = adj[j + 1];
        float4 v0 = *(const float4*)(X + (size_t)s0 * D + lane * 4);
        float4 v1 = *(const float4*)(X + (size_t)s1 * D + lane * 4);
        s.x += v0.x + v1.x; s.y += v0.y + v1.y; s.z += v0.z + v1.z; s.w += v0.w + v1.w;
    }
    if (j < end) {
        int s0 = adj[j];
        float4 v0 = *(const float4*)(X + (size_t)s0 * D + lane * 4);
        s.x += v0.x; s.y += v0.y; s.z += v0.z; s.w += v0.w;
    }
    float inv = (end > beg) ? 1.0f / (float)(end - beg) : 0.f;
    s.x *= inv; s.y *= inv; s.z *= inv; s.w *= inv;
    float* o = Out + (size_t)r * D + lane * 4;
    if (ACC) {
        float4 c = *(const float4*)o;
        s.x += c.x; s.y += c.y; s.z += c.z; s.w += c.w;
    }
    *(float4*)o = s;
}

// ---------------- misc ----------------
__global__ void add2_kernel(const float* __restrict__ a, const float* __restrict__ b,
                            float* __restrict__ o, int n)
{
    int i = blockIdx.x * blockDim.x + threadIdx.x;
    if (i < n) o[i] = a[i] + b[i];
}

__global__ void dot_kernel(const float* __restrict__ H, const float* __restrict__ w,
                           const float* __restrict__ db, float* __restrict__ out, int E)
{
    int e = blockIdx.x * blockDim.x + threadIdx.x;
    if (e >= E) return;
    const float4* h = (const float4*)(H + (size_t)e * 128);
    const float4* wv = (const float4*)w;
    float s = 0.f;
    #pragma unroll
    for (int i = 0; i < 32; ++i) {
        float4 a = h[i], b = wv[i];
        s += a.x * b.x + a.y * b.y + a.z * b.z + a.w * b.w;
    }
    out[e] = s + db[0];
}

// ---------------- launch ----------------
extern "C" void kernel_launch(void* const* d_in, const int* in_sizes, int n_in,
                              void* d_out, int out_size, void* d_ws, size_t ws_size,
                              hipStream_t stream)
{
    const float* x_news = (const float*)d_in[0];
    const float* x_kw   = (const float*)d_in[1];
    const float* x_st   = (const float*)d_in[2];
    const float* Wn = (const float*)d_in[3];  const float* bn = (const float*)d_in[4];
    const float* Wk = (const float*)d_in[5];  const float* bk = (const float*)d_in[6];
    const float* Wst = (const float*)d_in[7]; const float* bs = (const float*)d_in[8];
    const float* W1l = (const float*)d_in[9];  const float* b1 = (const float*)d_in[10];
    const float* W1r = (const float*)d_in[11];
    const float* W2l = (const float*)d_in[12]; const float* b2 = (const float*)d_in[13];
    const float* W2r = (const float*)d_in[14];
    const float* DW1 = (const float*)d_in[15]; const float* Db1 = (const float*)d_in[16];
    const float* DW2 = (const float*)d_in[17]; const float* Db2 = (const float*)d_in[18];
    const int* e_hk_src = (const int*)d_in[19];
    const int* e_hk_dst = (const int*)d_in[20];
    const int* e_hs_src = (const int*)d_in[21];
    const int* e_hs_dst = (const int*)d_in[22];
    const int* l_hk_src = (const int*)d_in[23];
    const int* l_hk_dst = (const int*)d_in[24];
    const int* l_hs_src = (const int*)d_in[25];
    const int* l_hs_dst = (const int*)d_in[26];
    float* out = (float*)d_out;

    // ---- workspace layout ----
    float* ws = (float*)d_ws;
    size_t o = 0;
    float* HN  = ws + o; o += (size_t)N_NEWS * HID;   // 12.80M
    float* HK  = ws + o; o += (size_t)N_KW * HID;     //  2.56M
    float* HS  = ws + o; o += (size_t)N_ST * HID;     //  0.512M
    float* K1  = ws + o; o += (size_t)N_KW * HID;     //  2.56M
    float* S1  = ws + o; o += (size_t)N_ST * HID;     //  0.512M
    float* P   = ws + o; o += (size_t)N_KW * HID;     //  2.56M
    float* P2  = ws + o; o += (size_t)N_ST * HID;     //  0.512M
    float* N1  = ws + o; o += (size_t)N_NEWS * HID;   // 12.80M
    float* WS1s = ws + o; o += 65536;                 // W1r[1]+W1r[3]
    float* WS2s = ws + o; o += 32768;                 // W2r[1]+W2r[3]
    float* BS1  = ws + o; o += 256;
    float* BS2  = ws + o; o += 128;
    // int section
    int* ib = (int*)(ws + o);
    size_t io = 0;
    int* curA = ib + io; io += N_KW;      // e_hk by dst(kw)
    int* curB = ib + io; io += N_ST;      // e_hs by dst(st)
    int* curC = ib + io; io += N_NEWS;    // e_hk by src(news)
    int* curD = ib + io; io += N_NEWS;    // e_hs by src(news)
    int* adjA = ib + io; io += E_HK;
    int* adjB = ib + io; io += E_HS;
    int* adjC = ib + io; io += E_HK;
    int* adjD = ib + io; io += E_HS;
    int* deg  = ib + io; io += N_NEWS;    // shared scratch
    int* bsum   = ib + io; io += 256;
    int* bsumex = ib + io; io += 256;
    // total ≈ 36.3M * 4B ≈ 145 MB

    // overlays: layer-2 outputs reuse HN (dead after layer 1)
    float* K2 = HN;                                   // 10000x128
    float* N2 = HN + (size_t)N_KW * OUTD;             // 50000x128
    float* S2 = N2 + (size_t)N_NEWS * OUTD;           //  2000x128
    // decoder hidden reuses HK..N1 (dead after layer 2): 19.2M <= 21.5M
    float* HB = HK;

    auto gemm = [&](const float* A, const int* ridx, int lda, const float* W, int ldw,
                    const float* bias, float* C, int ldc, int M, int N, int K, int flags) {
        dim3 g((M + BM - 1) / BM, (N + BN - 1) / BN);
        gemm_kernel<<<g, dim3(256), 0, stream>>>(A, ridx, lda, W, ldw, bias, C, ldc, M, N, K, flags);
    };
    auto build_csr = [&](const int* key, const int* val, int* cursor, int* adj, int E, int n) {
        hipMemsetAsync(deg, 0, (size_t)n * sizeof(int), stream);
        count_kernel<<<(E + 255) / 256, 256, 0, stream>>>(key, deg, E);
        int nb = (n + 255) / 256;
        scan_block_kernel<<<nb, 256, 0, stream>>>(deg, cursor, bsum, n);
        scan_block_kernel<<<1, 256, 0, stream>>>(bsum, bsumex, nullptr, nb);
        scan_add_kernel<<<nb, 256, 0, stream>>>(cursor, bsumex, n);
        csr_fill_kernel<<<(E + 255) / 256, 256, 0, stream>>>(key, val, cursor, adj, E);
    };

    // ---- CSRs for the 4 gather directions ----
    build_csr(e_hk_dst, e_hk_src, curA, adjA, E_HK, N_KW);
    build_csr(e_hs_dst, e_hs_src, curB, adjB, E_HS, N_ST);
    build_csr(e_hk_src, e_hk_dst, curC, adjC, E_HK, N_NEWS);
    build_csr(e_hs_src, e_hs_dst, curD, adjD, E_HS, N_NEWS);

    // ---- summed r-weights for the news target (relations 1 and 3) ----
    const size_t WS1 = (size_t)HID * HID;   // 65536
    const size_t WS2 = (size_t)OUTD * HID;  // 32768
    add2_kernel<<<(65536 + 255) / 256, 256, 0, stream>>>(W1r + 1 * WS1, W1r + 3 * WS1, WS1s, 65536);
    add2_kernel<<<(32768 + 255) / 256, 256, 0, stream>>>(W2r + 1 * WS2, W2r + 3 * WS2, WS2s, 32768);
    add2_kernel<<<1, 256, 0, stream>>>(b1 + 1 * HID, b1 + 3 * HID, BS1, 256);
    add2_kernel<<<1, 128, 0, stream>>>(b2 + 1 * OUTD, b2 + 3 * OUTD, BS2, 128);

    // ---- input projections ----
    gemm(x_news, nullptr, F_NEWS, Wn,  F_NEWS, bn, HN, HID, N_NEWS, HID, F_NEWS, FLAG_RELU);
    gemm(x_kw,   nullptr, F_KW,   Wk,  F_KW,   bk, HK, HID, N_KW,   HID, F_KW,   FLAG_RELU);
    gemm(x_st,   nullptr, F_ST,   Wst, F_ST,   bs, HS, HID, N_ST,   HID, F_ST,   FLAG_RELU);

    // ---- layer 1 ----
    // k1 = relu(mean_A(hn)@W1l0^T + b1[0] + hk@W1r0^T)
    gather_mean_kernel<256, false><<<(N_KW + 3) / 4, 256, 0, stream>>>(HN, curA, adjA, P, N_KW);
    gemm(P,  nullptr, HID, W1l + 0 * WS1, HID, b1 + 0 * HID, K1, HID, N_KW, HID, HID, 0);
    gemm(HK, nullptr, HID, W1r + 0 * WS1, HID, nullptr,      K1, HID, N_KW, HID, HID, FLAG_ACC | FLAG_RELU);
    // s1
    gather_mean_kernel<256, false><<<(N_ST + 3) / 4, 256, 0, stream>>>(HN, curB, adjB, P, N_ST);
    gemm(P,  nullptr, HID, W1l + 2 * WS1, HID, b1 + 2 * HID, S1, HID, N_ST, HID, HID, 0);
    gemm(HS, nullptr, HID, W1r + 2 * WS1, HID, nullptr,      S1, HID, N_ST, HID, HID, FLAG_ACC | FLAG_RELU);
    // n1 [project-first: project small sources, gather-mean into N1, then fused r-term]
    gemm(HK, nullptr, HID, W1l + 1 * WS1, HID, nullptr, P,  HID, N_KW, HID, HID, 0);
    gemm(HS, nullptr, HID, W1l + 3 * WS1, HID, nullptr, P2, HID, N_ST, HID, HID, 0);
    gather_mean_kernel<256, false><<<(N_NEWS + 3) / 4, 256, 0, stream>>>(P,  curC, adjC, N1, N_NEWS);
    gather_mean_kernel<256, true ><<<(N_NEWS + 3) / 4, 256, 0, stream>>>(P2, curD, adjD, N1, N_NEWS);
    gemm(HN, nullptr, HID, WS1s, HID, BS1, N1, HID, N_NEWS, HID, HID, FLAG_ACC | FLAG_RELU);

    // ---- layer 2 (no relu) ----
    // k2
    gather_mean_kernel<256, false><<<(N_KW + 3) / 4, 256, 0, stream>>>(N1, curA, adjA, P, N_KW);
    gemm(P,  nullptr, HID, W2l + 0 * WS2, HID, b2 + 0 * OUTD, K2, OUTD, N_KW, OUTD, HID, 0);
    gemm(K1, nullptr, HID, W2r + 0 * WS2, HID, nullptr,       K2, OUTD, N_KW, OUTD, HID, FLAG_ACC);
    // s2
    gather_mean_kernel<256, false><<<(N_ST + 3) / 4, 256, 0, stream>>>(N1, curB, adjB, P, N_ST);
    gemm(P,  nullptr, HID, W2l + 2 * WS2, HID, b2 + 2 * OUTD, S2, OUTD, N_ST, OUTD, HID, 0);
    gemm(S1, nullptr, HID, W2r + 2 * WS2, HID, nullptr,       S2, OUTD, N_ST, OUTD, HID, FLAG_ACC);
    // n2 [project-first]
    gemm(K1, nullptr, HID, W2l + 1 * WS2, HID, nullptr, P,  OUTD, N_KW, OUTD, HID, 0);
    gemm(S1, nullptr, HID, W2l + 3 * WS2, HID, nullptr, P2, OUTD, N_ST, OUTD, HID, 0);
    gather_mean_kernel<128, false><<<(N_NEWS + 7) / 8, 256, 0, stream>>>(P,  curC, adjC, N2, N_NEWS);
    gather_mean_kernel<128, true ><<<(N_NEWS + 7) / 8, 256, 0, stream>>>(P2, curD, adjD, N2, N_NEWS);
    gemm(N1, nullptr, HID, WS2s, HID, BS2, N2, OUTD, N_NEWS, OUTD, HID, FLAG_ACC);

    // ---- decoders ----
    const size_t DWS = (size_t)OUTD * (2 * OUTD); // 32768
    // has_keyword
    gemm(N2, l_hk_src, OUTD, DW1 + 0 * DWS,        2 * OUTD, Db1 + 0 * OUTD, HB, OUTD, E_LBL, OUTD, OUTD, 0);
    gemm(K2, l_hk_dst, OUTD, DW1 + 0 * DWS + OUTD, 2 * OUTD, nullptr,        HB, OUTD, E_LBL, OUTD, OUTD, FLAG_ACC | FLAG_RELU);
    dot_kernel<<<(E_LBL + 255) / 256, 256, 0, stream>>>(HB, DW2 + 0 * OUTD, Db2 + 0, out, E_LBL);
    // has_stock
    gemm(N2, l_hs_src, OUTD, DW1 + 1 * DWS,        2 * OUTD, Db1 + 1 * OUTD, HB, OUTD, E_LBL, OUTD, OUTD, 0);
    gemm(S2, l_hs_dst, OUTD, DW1 + 1 * DWS + OUTD, 2 * OUTD, nullptr,        HB, OUTD, E_LBL, OUTD, OUTD, FLAG_ACC | FLAG_RELU);
    dot_kernel<<<(E_LBL + 255) / 256, 256, 0, stream>>>(HB, DW2 + 1 * OUTD, Db2 + 1, out + E_LBL, E_LBL);
}

// Round 4
// 1449.924 us; speedup vs baseline: 7.4204x; 1.6670x over previous
//
#include <hip/hip_runtime.h>

// ---------------- problem constants (match reference) ----------------
constexpr int N_NEWS = 50000, N_KW = 10000, N_ST = 2000;
constexpr int F_NEWS = 768, F_KW = 128, F_ST = 64;
constexpr int HID = 256, OUTD = 128;
constexpr int E_HK = 500000, E_HS = 250000, E_LBL = 150000;

enum { FLAG_ACC = 1, FLAG_RELU = 2 };

typedef __attribute__((ext_vector_type(8))) short bf16x8;
typedef __attribute__((ext_vector_type(4))) float f32x4;

__device__ __forceinline__ unsigned bf16_rne(float x) {
    unsigned u = __builtin_bit_cast(unsigned, x);
    return (u + 0x7FFFu + ((u >> 16) & 1u)) >> 16;
}

// ---------------- split-bf16 MFMA GEMM ----------------
// C[M,N] = [C] + A'[M,K] @ W[N,K]^T [+bias] [relu],  A' row m = A[rowidx[m]] (or m)
// fp32 operands split to bf16 hi/lo in LDS; 3 MFMAs/product (hi*hi + hi*lo + lo*hi).
// Block: 256 threads = 4 waves (2x2), tile 128x128, BK=32.
#define BM 128
#define BN 128
#define BK 32
#define LDSW 40   // padded row: 32 bf16 + 8 pad = 80 B

__global__ __launch_bounds__(256) void mfma_gemm_kernel(
    const float* __restrict__ A, const int* __restrict__ rowidx, int lda,
    const float* __restrict__ W, int ldw,
    const float* __restrict__ bias,
    float* __restrict__ C, int ldc,
    int M, int N, int K, int flags)
{
    __shared__ unsigned short AhiL[BM][LDSW];
    __shared__ unsigned short AloL[BM][LDSW];
    __shared__ unsigned short BhiL[BN][LDSW];
    __shared__ unsigned short BloL[BN][LDSW];

    const int tid = threadIdx.x;
    const int bm = blockIdx.x * BM;
    const int bn = blockIdx.y * BN;
    const int l  = tid & 63;
    const int w  = tid >> 6;
    const int wm = w >> 1, wn = w & 1;
    const int lg = l >> 4, lr = l & 15;

    // staging assignment: 8 threads/row, 4 floats each, 32 rows/pass, 4 passes
    const int sr = tid >> 3;          // 0..31
    const int sc = (tid & 7) * 4;     // 0,4,...,28

    const float* aptr[4];
    const float* bptr[4];
    #pragma unroll
    for (int p = 0; p < 4; ++p) {
        int r = bm + p * 32 + sr;
        aptr[p] = (r < M) ? A + (size_t)(rowidx ? rowidx[r] : r) * lda : nullptr;
        bptr[p] = W + (size_t)(bn + p * 32 + sr) * ldw;   // N is multiple of BN
    }

    f32x4 acc[4][4];
    #pragma unroll
    for (int i = 0; i < 4; ++i)
        #pragma unroll
        for (int j = 0; j < 4; ++j) acc[i][j] = (f32x4){0.f, 0.f, 0.f, 0.f};

    for (int k0 = 0; k0 < K; k0 += BK) {
        float4 av[4], bv[4];
        #pragma unroll
        for (int p = 0; p < 4; ++p) {
            av[p] = aptr[p] ? *(const float4*)(aptr[p] + k0 + sc) : make_float4(0.f, 0.f, 0.f, 0.f);
            bv[p] = *(const float4*)(bptr[p] + k0 + sc);
        }
        __syncthreads();
        #pragma unroll
        for (int p = 0; p < 4; ++p) {
            int row = p * 32 + sr;
            float va[4] = {av[p].x, av[p].y, av[p].z, av[p].w};
            float vb[4] = {bv[p].x, bv[p].y, bv[p].z, bv[p].w};
            ushort ah[4], al[4], bh[4], bl[4];
            #pragma unroll
            for (int q = 0; q < 4; ++q) {
                unsigned h = bf16_rne(va[q]);
                float hf = __builtin_bit_cast(float, h << 16);
                ah[q] = (ushort)h;
                al[q] = (ushort)bf16_rne(va[q] - hf);
                h = bf16_rne(vb[q]);
                hf = __builtin_bit_cast(float, h << 16);
                bh[q] = (ushort)h;
                bl[q] = (ushort)bf16_rne(vb[q] - hf);
            }
            *(ushort4*)&AhiL[row][sc] = make_ushort4(ah[0], ah[1], ah[2], ah[3]);
            *(ushort4*)&AloL[row][sc] = make_ushort4(al[0], al[1], al[2], al[3]);
            *(ushort4*)&BhiL[row][sc] = make_ushort4(bh[0], bh[1], bh[2], bh[3]);
            *(ushort4*)&BloL[row][sc] = make_ushort4(bl[0], bl[1], bl[2], bl[3]);
        }
        __syncthreads();

        bf16x8 fah[4], fal[4], fbh[4], fbl[4];
        #pragma unroll
        for (int mt = 0; mt < 4; ++mt) {
            int r = wm * 64 + mt * 16 + lr;
            fah[mt] = *(const bf16x8*)&AhiL[r][lg * 8];
            fal[mt] = *(const bf16x8*)&AloL[r][lg * 8];
        }
        #pragma unroll
        for (int nt = 0; nt < 4; ++nt) {
            int c = wn * 64 + nt * 16 + lr;
            fbh[nt] = *(const bf16x8*)&BhiL[c][lg * 8];
            fbl[nt] = *(const bf16x8*)&BloL[c][lg * 8];
        }
        #pragma unroll
        for (int mt = 0; mt < 4; ++mt)
            #pragma unroll
            for (int nt = 0; nt < 4; ++nt) {
                acc[mt][nt] = __builtin_amdgcn_mfma_f32_16x16x32_bf16(fah[mt], fbh[nt], acc[mt][nt], 0, 0, 0);
                acc[mt][nt] = __builtin_amdgcn_mfma_f32_16x16x32_bf16(fah[mt], fbl[nt], acc[mt][nt], 0, 0, 0);
                acc[mt][nt] = __builtin_amdgcn_mfma_f32_16x16x32_bf16(fal[mt], fbh[nt], acc[mt][nt], 0, 0, 0);
            }
    }

    // epilogue: C/D layout col = lane&15, row = (lane>>4)*4 + j
    float biasv[4];
    int bcol[4];
    #pragma unroll
    for (int nt = 0; nt < 4; ++nt) {
        bcol[nt] = bn + wn * 64 + nt * 16 + lr;
        biasv[nt] = bias ? bias[bcol[nt]] : 0.f;
    }
    #pragma unroll
    for (int mt = 0; mt < 4; ++mt) {
        int row0 = bm + wm * 64 + mt * 16 + lg * 4;
        #pragma unroll
        for (int j = 0; j < 4; ++j) {
            int row = row0 + j;
            if (row >= M) continue;
            float* Crow = C + (size_t)row * ldc;
            #pragma unroll
            for (int nt = 0; nt < 4; ++nt) {
                float v = acc[mt][nt][j];
                if (flags & FLAG_ACC) v += Crow[bcol[nt]];
                v += biasv[nt];
                if (flags & FLAG_RELU) v = fmaxf(v, 0.f);
                Crow[bcol[nt]] = v;
            }
        }
    }
}

// ---------------- CSR build ----------------
__global__ void count_kernel(const int* __restrict__ key, int* __restrict__ deg, int E)
{
    int e = blockIdx.x * blockDim.x + threadIdx.x;
    if (e < E) atomicAdd(deg + key[e], 1);
}

__global__ void scan_block_kernel(const int* __restrict__ in, int* __restrict__ out,
                                  int* __restrict__ bsum, int n)
{
    __shared__ int tmp[256];
    int i = blockIdx.x * 256 + threadIdx.x;
    int v = (i < n) ? in[i] : 0;
    tmp[threadIdx.x] = v;
    __syncthreads();
    #pragma unroll
    for (int off = 1; off < 256; off <<= 1) {
        int t = (threadIdx.x >= off) ? tmp[threadIdx.x - off] : 0;
        __syncthreads();
        tmp[threadIdx.x] += t;
        __syncthreads();
    }
    if (i < n) out[i] = tmp[threadIdx.x] - v;
    if (threadIdx.x == 255 && bsum) bsum[blockIdx.x] = tmp[255];
}

__global__ void scan_add_kernel(int* __restrict__ out, const int* __restrict__ bsumex, int n)
{
    int i = blockIdx.x * 256 + threadIdx.x;
    if (i < n) out[i] += bsumex[blockIdx.x];
}

__global__ void csr_fill_kernel(const int* __restrict__ key, const int* __restrict__ val,
                                int* __restrict__ cursor, int* __restrict__ adj, int E)
{
    int e = blockIdx.x * blockDim.x + threadIdx.x;
    if (e < E) {
        int p = atomicAdd(cursor + key[e], 1);
        adj[p] = val[e];
    }
}

// ---------------- gather mean ----------------
template <int D, bool ACC>
__global__ void gather_mean_kernel(const float* __restrict__ X,
                                   const int* __restrict__ cursor,
                                   const int* __restrict__ adj,
                                   float* __restrict__ Out, int ndst)
{
    constexpr int LANES = D / 4;
    constexpr int RPB = 256 / LANES;
    int r = blockIdx.x * RPB + threadIdx.x / LANES;
    if (r >= ndst) return;
    int lane = threadIdx.x % LANES;
    int beg = (r == 0) ? 0 : cursor[r - 1];
    int end = cursor[r];
    float4 s = {0.f, 0.f, 0.f, 0.f};
    int j = beg;
    for (; j + 1 < end; j += 2) {
        int s0 = adj[j], s1 = adj[j + 1];
        float4 v0 = *(const float4*)(X + (size_t)s0 * D + lane * 4);
        float4 v1 = *(const float4*)(X + (size_t)s1 * D + lane * 4);
        s.x += v0.x + v1.x; s.y += v0.y + v1.y; s.z += v0.z + v1.z; s.w += v0.w + v1.w;
    }
    if (j < end) {
        int s0 = adj[j];
        float4 v0 = *(const float4*)(X + (size_t)s0 * D + lane * 4);
        s.x += v0.x; s.y += v0.y; s.z += v0.z; s.w += v0.w;
    }
    float inv = (end > beg) ? 1.0f / (float)(end - beg) : 0.f;
    s.x *= inv; s.y *= inv; s.z *= inv; s.w *= inv;
    float* o = Out + (size_t)r * D + lane * 4;
    if (ACC) {
        float4 c = *(const float4*)o;
        s.x += c.x; s.y += c.y; s.z += c.z; s.w += c.w;
    }
    *(float4*)o = s;
}

// ---------------- misc ----------------
__global__ void add2_kernel(const float* __restrict__ a, const float* __restrict__ b,
                            float* __restrict__ o, int n)
{
    int i = blockIdx.x * blockDim.x + threadIdx.x;
    if (i < n) o[i] = a[i] + b[i];
}

__global__ void dot_kernel(const float* __restrict__ H, const float* __restrict__ w,
                           const float* __restrict__ db, float* __restrict__ out, int E)
{
    int e = blockIdx.x * blockDim.x + threadIdx.x;
    if (e >= E) return;
    const float4* h = (const float4*)(H + (size_t)e * 128);
    const float4* wv = (const float4*)w;
    float s = 0.f;
    #pragma unroll
    for (int i = 0; i < 32; ++i) {
        float4 a = h[i], b = wv[i];
        s += a.x * b.x + a.y * b.y + a.z * b.z + a.w * b.w;
    }
    out[e] = s + db[0];
}

// ---------------- launch ----------------
extern "C" void kernel_launch(void* const* d_in, const int* in_sizes, int n_in,
                              void* d_out, int out_size, void* d_ws, size_t ws_size,
                              hipStream_t stream)
{
    const float* x_news = (const float*)d_in[0];
    const float* x_kw   = (const float*)d_in[1];
    const float* x_st   = (const float*)d_in[2];
    const float* Wn = (const float*)d_in[3];  const float* bn = (const float*)d_in[4];
    const float* Wk = (const float*)d_in[5];  const float* bk = (const float*)d_in[6];
    const float* Wst = (const float*)d_in[7]; const float* bs = (const float*)d_in[8];
    const float* W1l = (const float*)d_in[9];  const float* b1 = (const float*)d_in[10];
    const float* W1r = (const float*)d_in[11];
    const float* W2l = (const float*)d_in[12]; const float* b2 = (const float*)d_in[13];
    const float* W2r = (const float*)d_in[14];
    const float* DW1 = (const float*)d_in[15]; const float* Db1 = (const float*)d_in[16];
    const float* DW2 = (const float*)d_in[17]; const float* Db2 = (const float*)d_in[18];
    const int* e_hk_src = (const int*)d_in[19];
    const int* e_hk_dst = (const int*)d_in[20];
    const int* e_hs_src = (const int*)d_in[21];
    const int* e_hs_dst = (const int*)d_in[22];
    const int* l_hk_src = (const int*)d_in[23];
    const int* l_hk_dst = (const int*)d_in[24];
    const int* l_hs_src = (const int*)d_in[25];
    const int* l_hs_dst = (const int*)d_in[26];
    float* out = (float*)d_out;

    // ---- workspace layout ----
    float* ws = (float*)d_ws;
    size_t o = 0;
    float* HN  = ws + o; o += (size_t)N_NEWS * HID;
    float* HK  = ws + o; o += (size_t)N_KW * HID;
    float* HS  = ws + o; o += (size_t)N_ST * HID;
    float* K1  = ws + o; o += (size_t)N_KW * HID;
    float* S1  = ws + o; o += (size_t)N_ST * HID;
    float* P   = ws + o; o += (size_t)N_KW * HID;
    float* P2  = ws + o; o += (size_t)N_ST * HID;
    float* N1  = ws + o; o += (size_t)N_NEWS * HID;
    float* WS1s = ws + o; o += 65536;
    float* WS2s = ws + o; o += 32768;
    float* BS1  = ws + o; o += 256;
    float* BS2  = ws + o; o += 128;
    int* ib = (int*)(ws + o);
    size_t io = 0;
    int* curA = ib + io; io += N_KW;
    int* curB = ib + io; io += N_ST;
    int* curC = ib + io; io += N_NEWS;
    int* curD = ib + io; io += N_NEWS;
    int* adjA = ib + io; io += E_HK;
    int* adjB = ib + io; io += E_HS;
    int* adjC = ib + io; io += E_HK;
    int* adjD = ib + io; io += E_HS;
    int* deg  = ib + io; io += N_NEWS;
    int* bsum   = ib + io; io += 256;
    int* bsumex = ib + io; io += 256;

    float* K2 = HN;
    float* N2 = HN + (size_t)N_KW * OUTD;
    float* S2 = N2 + (size_t)N_NEWS * OUTD;
    float* HB = HK;

    auto gemm = [&](const float* A, const int* ridx, int lda, const float* W, int ldw,
                    const float* bias, float* C, int ldc, int M, int N, int K, int flags) {
        dim3 g((M + BM - 1) / BM, (N + BN - 1) / BN);
        mfma_gemm_kernel<<<g, dim3(256), 0, stream>>>(A, ridx, lda, W, ldw, bias, C, ldc, M, N, K, flags);
    };
    auto build_csr = [&](const int* key, const int* val, int* cursor, int* adj, int E, int n) {
        hipMemsetAsync(deg, 0, (size_t)n * sizeof(int), stream);
        count_kernel<<<(E + 255) / 256, 256, 0, stream>>>(key, deg, E);
        int nb = (n + 255) / 256;
        scan_block_kernel<<<nb, 256, 0, stream>>>(deg, cursor, bsum, n);
        scan_block_kernel<<<1, 256, 0, stream>>>(bsum, bsumex, nullptr, nb);
        scan_add_kernel<<<nb, 256, 0, stream>>>(cursor, bsumex, n);
        csr_fill_kernel<<<(E + 255) / 256, 256, 0, stream>>>(key, val, cursor, adj, E);
    };

    // ---- CSRs for the 4 gather directions ----
    build_csr(e_hk_dst, e_hk_src, curA, adjA, E_HK, N_KW);
    build_csr(e_hs_dst, e_hs_src, curB, adjB, E_HS, N_ST);
    build_csr(e_hk_src, e_hk_dst, curC, adjC, E_HK, N_NEWS);
    build_csr(e_hs_src, e_hs_dst, curD, adjD, E_HS, N_NEWS);

    // ---- summed r-weights for the news target ----
    const size_t WS1 = (size_t)HID * HID;
    const size_t WS2 = (size_t)OUTD * HID;
    add2_kernel<<<(65536 + 255) / 256, 256, 0, stream>>>(W1r + 1 * WS1, W1r + 3 * WS1, WS1s, 65536);
    add2_kernel<<<(32768 + 255) / 256, 256, 0, stream>>>(W2r + 1 * WS2, W2r + 3 * WS2, WS2s, 32768);
    add2_kernel<<<1, 256, 0, stream>>>(b1 + 1 * HID, b1 + 3 * HID, BS1, 256);
    add2_kernel<<<1, 128, 0, stream>>>(b2 + 1 * OUTD, b2 + 3 * OUTD, BS2, 128);

    // ---- input projections ----
    gemm(x_news, nullptr, F_NEWS, Wn,  F_NEWS, bn, HN, HID, N_NEWS, HID, F_NEWS, FLAG_RELU);
    gemm(x_kw,   nullptr, F_KW,   Wk,  F_KW,   bk, HK, HID, N_KW,   HID, F_KW,   FLAG_RELU);
    gemm(x_st,   nullptr, F_ST,   Wst, F_ST,   bs, HS, HID, N_ST,   HID, F_ST,   FLAG_RELU);

    // ---- layer 1 ----
    gather_mean_kernel<256, false><<<(N_KW + 3) / 4, 256, 0, stream>>>(HN, curA, adjA, P, N_KW);
    gemm(P,  nullptr, HID, W1l + 0 * WS1, HID, b1 + 0 * HID, K1, HID, N_KW, HID, HID, 0);
    gemm(HK, nullptr, HID, W1r + 0 * WS1, HID, nullptr,      K1, HID, N_KW, HID, HID, FLAG_ACC | FLAG_RELU);
    gather_mean_kernel<256, false><<<(N_ST + 3) / 4, 256, 0, stream>>>(HN, curB, adjB, P, N_ST);
    gemm(P,  nullptr, HID, W1l + 2 * WS1, HID, b1 + 2 * HID, S1, HID, N_ST, HID, HID, 0);
    gemm(HS, nullptr, HID, W1r + 2 * WS1, HID, nullptr,      S1, HID, N_ST, HID, HID, FLAG_ACC | FLAG_RELU);
    gemm(HK, nullptr, HID, W1l + 1 * WS1, HID, nullptr, P,  HID, N_KW, HID, HID, 0);
    gemm(HS, nullptr, HID, W1l + 3 * WS1, HID, nullptr, P2, HID, N_ST, HID, HID, 0);
    gather_mean_kernel<256, false><<<(N_NEWS + 3) / 4, 256, 0, stream>>>(P,  curC, adjC, N1, N_NEWS);
    gather_mean_kernel<256, true ><<<(N_NEWS + 3) / 4, 256, 0, stream>>>(P2, curD, adjD, N1, N_NEWS);
    gemm(HN, nullptr, HID, WS1s, HID, BS1, N1, HID, N_NEWS, HID, HID, FLAG_ACC | FLAG_RELU);

    // ---- layer 2 ----
    gather_mean_kernel<256, false><<<(N_KW + 3) / 4, 256, 0, stream>>>(N1, curA, adjA, P, N_KW);
    gemm(P,  nullptr, HID, W2l + 0 * WS2, HID, b2 + 0 * OUTD, K2, OUTD, N_KW, OUTD, HID, 0);
    gemm(K1, nullptr, HID, W2r + 0 * WS2, HID, nullptr,       K2, OUTD, N_KW, OUTD, HID, FLAG_ACC);
    gather_mean_kernel<256, false><<<(N_ST + 3) / 4, 256, 0, stream>>>(N1, curB, adjB, P, N_ST);
    gemm(P,  nullptr, HID, W2l + 2 * WS2, HID, b2 + 2 * OUTD, S2, OUTD, N_ST, OUTD, HID, 0);
    gemm(S1, nullptr, HID, W2r + 2 * WS2, HID, nullptr,       S2, OUTD, N_ST, OUTD, HID, FLAG_ACC);
    gemm(K1, nullptr, HID, W2l + 1 * WS2, HID, nullptr, P,  OUTD, N_KW, OUTD, HID, 0);
    gemm(S1, nullptr, HID, W2l + 3 * WS2, HID, nullptr, P2, OUTD, N_ST, OUTD, HID, 0);
    gather_mean_kernel<128, false><<<(N_NEWS + 7) / 8, 256, 0, stream>>>(P,  curC, adjC, N2, N_NEWS);
    gather_mean_kernel<128, true ><<<(N_NEWS + 7) / 8, 256, 0, stream>>>(P2, curD, adjD, N2, N_NEWS);
    gemm(N1, nullptr, HID, WS2s, HID, BS2, N2, OUTD, N_NEWS, OUTD, HID, FLAG_ACC);

    // ---- decoders ----
    const size_t DWS = (size_t)OUTD * (2 * OUTD);
    gemm(N2, l_hk_src, OUTD, DW1 + 0 * DWS,        2 * OUTD, Db1 + 0 * OUTD, HB, OUTD, E_LBL, OUTD, OUTD, 0);
    gemm(K2, l_hk_dst, OUTD, DW1 + 0 * DWS + OUTD, 2 * OUTD, nullptr,        HB, OUTD, E_LBL, OUTD, OUTD, FLAG_ACC | FLAG_RELU);
    dot_kernel<<<(E_LBL + 255) / 256, 256, 0, stream>>>(HB, DW2 + 0 * OUTD, Db2 + 0, out, E_LBL);
    gemm(N2, l_hs_src, OUTD, DW1 + 1 * DWS,        2 * OUTD, Db1 + 1 * OUTD, HB, OUTD, E_LBL, OUTD, OUTD, 0);
    gemm(S2, l_hs_dst, OUTD, DW1 + 1 * DWS + OUTD, 2 * OUTD, nullptr,        HB, OUTD, E_LBL, OUTD, OUTD, FLAG_ACC | FLAG_RELU);
    dot_kernel<<<(E_LBL + 255) / 256, 256, 0, stream>>>(HB, DW2 + 1 * OUTD, Db2 + 1, out + E_LBL, E_LBL);
}

// Round 5
// 1105.142 us; speedup vs baseline: 9.7354x; 1.3120x over previous
//
#include <hip/hip_runtime.h>
#include <hip/hip_bf16.h>

// ---------------- problem constants ----------------
constexpr int N_NEWS = 50000, N_KW = 10000, N_ST = 2000;
constexpr int F_NEWS = 768, F_KW = 128, F_ST = 64;
constexpr int HID = 256, OUTD = 128;
constexpr int E_HK = 500000, E_HS = 250000, E_LBL = 150000;

// CSR section offsets in the concatenated degree/cursor pools
constexpr int OFFA = 0;                    // e_hk keyed by dst (kw)
constexpr int OFFB = N_KW;                 // e_hs keyed by dst (st)
constexpr int OFFC = N_KW + N_ST;          // e_hk keyed by src (news)
constexpr int OFFD = OFFC + N_NEWS;        // e_hs keyed by src (news)
constexpr int NTOT = OFFD + N_NEWS;        // 112000

enum { FLAG_ACC = 1, FLAG_RELU = 2 };

typedef unsigned short u16;
typedef __attribute__((ext_vector_type(8))) short bf16x8;
typedef __attribute__((ext_vector_type(8))) unsigned short u16x8;
typedef __attribute__((ext_vector_type(4))) float f32x4;

__device__ __forceinline__ u16 f2bf(float x) {
    return __builtin_bit_cast(u16, __float2bfloat16(x));
}
__device__ __forceinline__ float bf2f(u16 h) {
    unsigned u = ((unsigned)h) << 16;
    return __builtin_bit_cast(float, u);
}
__device__ __forceinline__ void split2(float x, u16& h, u16& l) {
    h = f2bf(x);
    l = f2bf(x - bf2f(h));
}

// ---------------- split-bf16 MFMA GEMM, swizzled LDS ----------------
// tile 128x128, BK=32, 4 waves (2x2). 3 MFMA/product (hi*hi+hi*lo+lo*hi), LOWP: 1.
// ASRC: 0 = fp32 A (convert in staging), 1 = plane A, 2 = dual-plane A (decoder concat)
// WMODE: 0 = write hi+lo planes, 1 = write hi plane only, 2 = fused decoder reduce->outv
template<int ASRC, int WMODE, bool LOWP>
__global__ __launch_bounds__(256) void gemm_kernel(
    const float* __restrict__ Af,
    const u16* __restrict__ A1h, const u16* __restrict__ A1l,
    const u16* __restrict__ A2h, const u16* __restrict__ A2l,
    const int* __restrict__ ridx1, const int* __restrict__ ridx2, int lda,
    const u16* __restrict__ Bhg, const u16* __restrict__ Blg, int ldw,
    const float* __restrict__ bias,
    u16* __restrict__ Chi, u16* __restrict__ Clo, int ldc,
    const float* __restrict__ dw2, const float* __restrict__ db2,
    float* __restrict__ outv,
    int M, int N, int K, int flags)
{
    __shared__ u16 Ah[128 * 32], Bh[128 * 32];
    __shared__ u16 Al[128 * 32], Bl[128 * 32];
    __shared__ float red[128];

    const int tid = threadIdx.x;
    const int bm = blockIdx.x * 128;
    const int bn = blockIdx.y * 128;
    const int l = tid & 63;
    const int w = tid >> 6;
    const int wm = w >> 1, wn = w & 1;
    const int lg = l >> 4, lr = l & 15;

    f32x4 acc[4][4];
    #pragma unroll
    for (int i = 0; i < 4; ++i)
        #pragma unroll
        for (int j = 0; j < 4; ++j) acc[i][j] = (f32x4){0.f, 0.f, 0.f, 0.f};

    for (int k0 = 0; k0 < K; k0 += 32) {
        __syncthreads();
        #pragma unroll
        for (int pass = 0; pass < 2; ++pass) {
            int g = tid + pass * 256;
            int row = g >> 2;
            int c8 = (g & 3) * 8;
            int usw = (row * 32 + c8) ^ ((row & 7) << 3);
            int rg = bm + row; if (rg > M - 1) rg = M - 1;
            // ---- A ----
            if constexpr (ASRC == 0) {
                long ar = ridx1 ? (long)ridx1[rg] : (long)rg;
                const float* pa = Af + ar * lda + k0 + c8;
                float4 v0 = ((const float4*)pa)[0];
                float4 v1 = ((const float4*)pa)[1];
                float vv[8] = {v0.x, v0.y, v0.z, v0.w, v1.x, v1.y, v1.z, v1.w};
                u16x8 h8, l8;
                #pragma unroll
                for (int q = 0; q < 8; ++q) { u16 hh, ll; split2(vv[q], hh, ll); h8[q] = hh; l8[q] = ll; }
                *(u16x8*)&Ah[usw] = h8;
                *(u16x8*)&Al[usw] = l8;
            } else if constexpr (ASRC == 1) {
                long ar = ridx1 ? (long)ridx1[rg] : (long)rg;
                *(u16x8*)&Ah[usw] = *(const u16x8*)(A1h + ar * lda + k0 + c8);
                if constexpr (!LOWP)
                    *(u16x8*)&Al[usw] = *(const u16x8*)(A1l + ar * lda + k0 + c8);
            } else {
                const u16 *ph, *pl;
                if (k0 < 128) { long ar = (long)ridx1[rg]; ph = A1h + ar * 128 + k0 + c8;        pl = A1l + ar * 128 + k0 + c8; }
                else          { long ar = (long)ridx2[rg]; ph = A2h + ar * 128 + (k0 - 128) + c8; pl = A2l + ar * 128 + (k0 - 128) + c8; }
                *(u16x8*)&Ah[usw] = *(const u16x8*)ph;
                *(u16x8*)&Al[usw] = *(const u16x8*)pl;
            }
            // ---- B (always planes) ----
            {
                long br = bn + row;
                *(u16x8*)&Bh[usw] = *(const u16x8*)(Bhg + br * ldw + k0 + c8);
                if constexpr (!LOWP)
                    *(u16x8*)&Bl[usw] = *(const u16x8*)(Blg + br * ldw + k0 + c8);
            }
        }
        __syncthreads();

        bf16x8 fah[4], fal[4], fbh[4], fbl[4];
        #pragma unroll
        for (int mt = 0; mt < 4; ++mt) {
            int r = wm * 64 + mt * 16 + lr;
            int us = (r * 32 + lg * 8) ^ ((r & 7) << 3);
            fah[mt] = *(const bf16x8*)&Ah[us];
            if constexpr (!LOWP) fal[mt] = *(const bf16x8*)&Al[us];
        }
        #pragma unroll
        for (int nt = 0; nt < 4; ++nt) {
            int r = wn * 64 + nt * 16 + lr;
            int us = (r * 32 + lg * 8) ^ ((r & 7) << 3);
            fbh[nt] = *(const bf16x8*)&Bh[us];
            if constexpr (!LOWP) fbl[nt] = *(const bf16x8*)&Bl[us];
        }
        #pragma unroll
        for (int mt = 0; mt < 4; ++mt)
            #pragma unroll
            for (int nt = 0; nt < 4; ++nt) {
                acc[mt][nt] = __builtin_amdgcn_mfma_f32_16x16x32_bf16(fah[mt], fbh[nt], acc[mt][nt], 0, 0, 0);
                if constexpr (!LOWP) {
                    acc[mt][nt] = __builtin_amdgcn_mfma_f32_16x16x32_bf16(fah[mt], fbl[nt], acc[mt][nt], 0, 0, 0);
                    acc[mt][nt] = __builtin_amdgcn_mfma_f32_16x16x32_bf16(fal[mt], fbh[nt], acc[mt][nt], 0, 0, 0);
                }
            }
    }

    if constexpr (WMODE == 2) {
        // fused decoder: out[row] = sum_col relu(acc+bias)*dw2[col] + db2
        if (tid < 128) red[tid] = 0.f;
        __syncthreads();
        float bv[4], dwv[4];
        #pragma unroll
        for (int nt = 0; nt < 4; ++nt) {
            int colg = wn * 64 + nt * 16 + lr;
            bv[nt] = bias[colg];
            dwv[nt] = dw2[colg];
        }
        #pragma unroll
        for (int mt = 0; mt < 4; ++mt)
            #pragma unroll
            for (int j = 0; j < 4; ++j) {
                float p = 0.f;
                #pragma unroll
                for (int nt = 0; nt < 4; ++nt)
                    p += fmaxf(acc[mt][nt][j] + bv[nt], 0.f) * dwv[nt];
                p += __shfl_xor(p, 1);
                p += __shfl_xor(p, 2);
                p += __shfl_xor(p, 4);
                p += __shfl_xor(p, 8);
                if (lr == 0) atomicAdd(&red[wm * 64 + mt * 16 + lg * 4 + j], p);
            }
        __syncthreads();
        if (tid < 128) {
            int row = bm + tid;
            if (row < M) outv[row] = red[tid] + db2[0];
        }
    } else {
        float bv[4];
        int col[4];
        #pragma unroll
        for (int nt = 0; nt < 4; ++nt) {
            col[nt] = bn + wn * 64 + nt * 16 + lr;
            bv[nt] = bias ? bias[col[nt]] : 0.f;
        }
        #pragma unroll
        for (int mt = 0; mt < 4; ++mt) {
            int row0 = bm + wm * 64 + mt * 16 + lg * 4;
            #pragma unroll
            for (int j = 0; j < 4; ++j) {
                int row = row0 + j;
                if (row >= M) continue;
                size_t rbase = (size_t)row * ldc;
                #pragma unroll
                for (int nt = 0; nt < 4; ++nt) {
                    size_t off = rbase + col[nt];
                    float v = acc[mt][nt][j];
                    if (flags & FLAG_ACC) v += bf2f(Chi[off]) + bf2f(Clo[off]);
                    v += bv[nt];
                    if (flags & FLAG_RELU) v = fmaxf(v, 0.f);
                    u16 hh, ll; split2(v, hh, ll);
                    Chi[off] = hh;
                    if constexpr (WMODE == 0) Clo[off] = ll;
                }
            }
        }
    }
}

// ---------------- CSR build (batched, sections A|B|C|D) ----------------
__global__ void count_hk_kernel(const int* __restrict__ src, const int* __restrict__ dst,
                                int* __restrict__ deg, int E)
{
    int e = blockIdx.x * blockDim.x + threadIdx.x;
    if (e < E) {
        atomicAdd(deg + OFFA + dst[e], 1);
        atomicAdd(deg + OFFC + src[e], 1);
    }
}
__global__ void count_hs_kernel(const int* __restrict__ src, const int* __restrict__ dst,
                                int* __restrict__ deg, int E)
{
    int e = blockIdx.x * blockDim.x + threadIdx.x;
    if (e < E) {
        atomicAdd(deg + OFFB + dst[e], 1);
        atomicAdd(deg + OFFD + src[e], 1);
    }
}

__global__ void scan_block_kernel(const int* __restrict__ in, int* __restrict__ out,
                                  int* __restrict__ bsum, int n)
{
    __shared__ int tmp[256];
    int i = blockIdx.x * 256 + threadIdx.x;
    int v = (i < n) ? in[i] : 0;
    tmp[threadIdx.x] = v;
    __syncthreads();
    #pragma unroll
    for (int off = 1; off < 256; off <<= 1) {
        int t = (threadIdx.x >= off) ? tmp[threadIdx.x - off] : 0;
        __syncthreads();
        tmp[threadIdx.x] += t;
        __syncthreads();
    }
    if (i < n) out[i] = tmp[threadIdx.x] - v;
    if (threadIdx.x == 255 && bsum) bsum[blockIdx.x] = tmp[255];
}

__global__ void scan2_kernel(int* __restrict__ data, int n) // n <= 512, in-place exclusive
{
    __shared__ int tmp[512];
    int v = (threadIdx.x < n) ? data[threadIdx.x] : 0;
    tmp[threadIdx.x] = v;
    __syncthreads();
    #pragma unroll
    for (int off = 1; off < 512; off <<= 1) {
        int t = (threadIdx.x >= off) ? tmp[threadIdx.x - off] : 0;
        __syncthreads();
        tmp[threadIdx.x] += t;
        __syncthreads();
    }
    if (threadIdx.x < n) data[threadIdx.x] = tmp[threadIdx.x] - v;
}

__global__ void scan_add_kernel(int* __restrict__ out, const int* __restrict__ bsumex, int n)
{
    int i = blockIdx.x * 256 + threadIdx.x;
    if (i < n) out[i] += bsumex[blockIdx.x];
}

__global__ void fill_hk_kernel(const int* __restrict__ src, const int* __restrict__ dst,
                               int* __restrict__ cur, u16* __restrict__ adj, int E)
{
    int e = blockIdx.x * blockDim.x + threadIdx.x;
    if (e < E) {
        int s = src[e], d = dst[e];
        int p = atomicAdd(cur + OFFA + d, 1); adj[p] = (u16)s;
        int q = atomicAdd(cur + OFFC + s, 1); adj[q] = (u16)d;
    }
}
__global__ void fill_hs_kernel(const int* __restrict__ src, const int* __restrict__ dst,
                               int* __restrict__ cur, u16* __restrict__ adj, int E)
{
    int e = blockIdx.x * blockDim.x + threadIdx.x;
    if (e < E) {
        int s = src[e], d = dst[e];
        int p = atomicAdd(cur + OFFB + d, 1); adj[p] = (u16)s;
        int q = atomicAdd(cur + OFFD + s, 1); adj[q] = (u16)d;
    }
}

// ---------------- gather mean (hi-plane read, hi/lo write) ----------------
template <int D>
__global__ void gather_mean_kernel(const u16* __restrict__ Xhi,
                                   const int* __restrict__ cur, const int* __restrict__ deg,
                                   const u16* __restrict__ adj,
                                   u16* __restrict__ Ohi, u16* __restrict__ Olo, int ndst)
{
    constexpr int LANES = D / 4;
    constexpr int RPB = 256 / LANES;
    int r = blockIdx.x * RPB + threadIdx.x / LANES;
    if (r >= ndst) return;
    int lane = threadIdx.x % LANES;
    int end = cur[r];
    int n = deg[r];
    int j = end - n;
    float4 s = {0.f, 0.f, 0.f, 0.f};
    for (; j + 1 < end; j += 2) {
        int s0 = adj[j], s1 = adj[j + 1];
        ushort4 a = *(const ushort4*)(Xhi + (size_t)s0 * D + lane * 4);
        ushort4 b = *(const ushort4*)(Xhi + (size_t)s1 * D + lane * 4);
        s.x += bf2f(a.x) + bf2f(b.x); s.y += bf2f(a.y) + bf2f(b.y);
        s.z += bf2f(a.z) + bf2f(b.z); s.w += bf2f(a.w) + bf2f(b.w);
    }
    if (j < end) {
        ushort4 a = *(const ushort4*)(Xhi + (size_t)adj[j] * D + lane * 4);
        s.x += bf2f(a.x); s.y += bf2f(a.y); s.z += bf2f(a.z); s.w += bf2f(a.w);
    }
    float inv = (n > 0) ? 1.0f / (float)n : 0.f;
    s.x *= inv; s.y *= inv; s.z *= inv; s.w *= inv;
    size_t off = (size_t)r * D + lane * 4;
    ushort4 h, l;
    split2(s.x, h.x, l.x); split2(s.y, h.y, l.y); split2(s.z, h.z, l.z); split2(s.w, h.w, l.w);
    *(ushort4*)(Ohi + off) = h;
    *(ushort4*)(Olo + off) = l;
}

// ---------------- fused news assembly: N += meanC(PP) + meanD(PP2); [relu] ----------------
template <int D, bool RELU>
__global__ void fuse_news_kernel(const u16* __restrict__ PPh, const u16* __restrict__ PP2h,
                                 const int* __restrict__ curC, const int* __restrict__ degC,
                                 const int* __restrict__ curD, const int* __restrict__ degD,
                                 const u16* __restrict__ adj,
                                 u16* __restrict__ Nh, u16* __restrict__ Nl, int ndst)
{
    constexpr int LANES = D / 4;
    constexpr int RPB = 256 / LANES;
    int r = blockIdx.x * RPB + threadIdx.x / LANES;
    if (r >= ndst) return;
    int lane = threadIdx.x % LANES;
    float4 s = {0.f, 0.f, 0.f, 0.f};
    {
        int end = curC[r], n = degC[r];
        float4 a = {0.f, 0.f, 0.f, 0.f};
        for (int j = end - n; j < end; ++j) {
            ushort4 v = *(const ushort4*)(PPh + (size_t)adj[j] * D + lane * 4);
            a.x += bf2f(v.x); a.y += bf2f(v.y); a.z += bf2f(v.z); a.w += bf2f(v.w);
        }
        float inv = (n > 0) ? 1.0f / (float)n : 0.f;
        s.x += a.x * inv; s.y += a.y * inv; s.z += a.z * inv; s.w += a.w * inv;
    }
    {
        int end = curD[r], n = degD[r];
        float4 a = {0.f, 0.f, 0.f, 0.f};
        for (int j = end - n; j < end; ++j) {
            ushort4 v = *(const ushort4*)(PP2h + (size_t)adj[j] * D + lane * 4);
            a.x += bf2f(v.x); a.y += bf2f(v.y); a.z += bf2f(v.z); a.w += bf2f(v.w);
        }
        float inv = (n > 0) ? 1.0f / (float)n : 0.f;
        s.x += a.x * inv; s.y += a.y * inv; s.z += a.z * inv; s.w += a.w * inv;
    }
    size_t off = (size_t)r * D + lane * 4;
    ushort4 h = *(const ushort4*)(Nh + off);
    ushort4 l = *(const ushort4*)(Nl + off);
    s.x += bf2f(h.x) + bf2f(l.x); s.y += bf2f(h.y) + bf2f(l.y);
    s.z += bf2f(h.z) + bf2f(l.z); s.w += bf2f(h.w) + bf2f(l.w);
    if (RELU) {
        s.x = fmaxf(s.x, 0.f); s.y = fmaxf(s.y, 0.f);
        s.z = fmaxf(s.z, 0.f); s.w = fmaxf(s.w, 0.f);
    }
    ushort4 oh, ol;
    split2(s.x, oh.x, ol.x); split2(s.y, oh.y, ol.y); split2(s.z, oh.z, ol.z); split2(s.w, oh.w, ol.w);
    *(ushort4*)(Nh + off) = oh;
    *(ushort4*)(Nl + off) = ol;
}

// ---------------- converts ----------------
__global__ void split_kernel(const float* __restrict__ src, u16* __restrict__ hi,
                             u16* __restrict__ lo, int n)
{
    int i = (blockIdx.x * 256 + threadIdx.x) * 4;
    if (i >= n) return;
    float4 v = *(const float4*)(src + i);
    ushort4 h, l;
    split2(v.x, h.x, l.x); split2(v.y, h.y, l.y); split2(v.z, h.z, l.z); split2(v.w, h.w, l.w);
    *(ushort4*)(hi + i) = h;
    *(ushort4*)(lo + i) = l;
}

__global__ void add2split_kernel(const float* __restrict__ a, const float* __restrict__ b,
                                 u16* __restrict__ hi, u16* __restrict__ lo, int n)
{
    int i = (blockIdx.x * 256 + threadIdx.x) * 4;
    if (i >= n) return;
    float4 va = *(const float4*)(a + i);
    float4 vb = *(const float4*)(b + i);
    float4 v = make_float4(va.x + vb.x, va.y + vb.y, va.z + vb.z, va.w + vb.w);
    ushort4 h, l;
    split2(v.x, h.x, l.x); split2(v.y, h.y, l.y); split2(v.z, h.z, l.z); split2(v.w, h.w, l.w);
    *(ushort4*)(hi + i) = h;
    *(ushort4*)(lo + i) = l;
}

__global__ void add2_kernel(const float* __restrict__ a, const float* __restrict__ b,
                            float* __restrict__ o, int n)
{
    int i = blockIdx.x * blockDim.x + threadIdx.x;
    if (i < n) o[i] = a[i] + b[i];
}

// ---------------- launch ----------------
extern "C" void kernel_launch(void* const* d_in, const int* in_sizes, int n_in,
                              void* d_out, int out_size, void* d_ws, size_t ws_size,
                              hipStream_t stream)
{
    const float* x_news = (const float*)d_in[0];
    const float* x_kw   = (const float*)d_in[1];
    const float* x_st   = (const float*)d_in[2];
    const float* Wn = (const float*)d_in[3];  const float* bn = (const float*)d_in[4];
    const float* Wk = (const float*)d_in[5];  const float* bk = (const float*)d_in[6];
    const float* Wst = (const float*)d_in[7]; const float* bs = (const float*)d_in[8];
    const float* W1l = (const float*)d_in[9];  const float* b1 = (const float*)d_in[10];
    const float* W1r = (const float*)d_in[11];
    const float* W2l = (const float*)d_in[12]; const float* b2 = (const float*)d_in[13];
    const float* W2r = (const float*)d_in[14];
    const float* DW1 = (const float*)d_in[15]; const float* Db1 = (const float*)d_in[16];
    const float* DW2 = (const float*)d_in[17]; const float* Db2 = (const float*)d_in[18];
    const int* e_hk_src = (const int*)d_in[19];
    const int* e_hk_dst = (const int*)d_in[20];
    const int* e_hs_src = (const int*)d_in[21];
    const int* e_hs_dst = (const int*)d_in[22];
    const int* l_hk_src = (const int*)d_in[23];
    const int* l_hk_dst = (const int*)d_in[24];
    const int* l_hs_src = (const int*)d_in[25];
    const int* l_hs_dst = (const int*)d_in[26];
    float* out = (float*)d_out;

    // ---- workspace layout (bytes, 16B aligned) ----
    char* base = (char*)d_ws;
    auto alloc = [&](size_t bytes) -> char* {
        char* p = base;
        base += (bytes + 15) & ~(size_t)15;
        return p;
    };
    auto aplane = [&](size_t elems) -> u16* { return (u16*)alloc(elems * 2); };

    u16* HNh = aplane((size_t)N_NEWS * HID);  u16* HNl = aplane((size_t)N_NEWS * HID);
    u16* HKh = aplane((size_t)N_KW * HID);    u16* HKl = aplane((size_t)N_KW * HID);
    u16* HSh = aplane((size_t)N_ST * HID);    u16* HSl = aplane((size_t)N_ST * HID);
    u16* K1h = aplane((size_t)N_KW * HID);    u16* K1l = aplane((size_t)N_KW * HID);
    u16* S1h = aplane((size_t)N_ST * HID);    u16* S1l = aplane((size_t)N_ST * HID);
    u16* PAh = aplane((size_t)N_KW * HID);    u16* PAl = aplane((size_t)N_KW * HID);
    u16* N1h = aplane((size_t)N_NEWS * HID);  u16* N1l = aplane((size_t)N_NEWS * HID);
    // weight planes
    u16* WnH = aplane(196608);  u16* WnL = aplane(196608);
    u16* WkH = aplane(32768);   u16* WkL = aplane(32768);
    u16* WsH = aplane(16384);   u16* WsL = aplane(16384);
    u16* W1lH = aplane(262144); u16* W1lL = aplane(262144);
    u16* W1r0H = aplane(65536); u16* W1r0L = aplane(65536);
    u16* W1r2H = aplane(65536); u16* W1r2L = aplane(65536);
    u16* W2lH = aplane(131072); u16* W2lL = aplane(131072);
    u16* W2r0H = aplane(32768); u16* W2r0L = aplane(32768);
    u16* W2r2H = aplane(32768); u16* W2r2L = aplane(32768);
    u16* DW1H = aplane(65536);  u16* DW1L = aplane(65536);
    u16* SW1H = aplane(65536);  u16* SW1L = aplane(65536);  // W1r[1]+W1r[3]
    u16* SW2H = aplane(32768);  u16* SW2L = aplane(32768);  // W2r[1]+W2r[3]
    float* BS1 = (float*)alloc(256 * 4);
    float* BS2 = (float*)alloc(128 * 4);
    // int pools
    int* deg = (int*)alloc((size_t)NTOT * 4);
    int* cur = (int*)alloc((size_t)NTOT * 4);
    u16* adj = (u16*)alloc((size_t)2 * (E_HK + E_HS) * 2);
    int* bsum = (int*)alloc(512 * 4);

    // overlays: layer-2 outputs reuse the HN region (dead after layer 1)
    u16* K2h = HNh;
    u16* K2l = K2h + (size_t)N_KW * OUTD;
    u16* N2h = K2l + (size_t)N_KW * OUTD;
    u16* N2l = N2h + (size_t)N_NEWS * OUTD;
    u16* S2h = N2l + (size_t)N_NEWS * OUTD;
    u16* S2l = S2h + (size_t)N_ST * OUTD;
    // PP/PP2 (hi-only projected sources) overlay PA planes (dead during n-phases)
    // layer1: PPh=PAh (10000x256), PP2h=PAl (2000x256); layer2: widths 128.

    // ---- CSR build ----
    hipMemsetAsync(deg, 0, (size_t)NTOT * sizeof(int), stream);
    count_hk_kernel<<<(E_HK + 255) / 256, 256, 0, stream>>>(e_hk_src, e_hk_dst, deg, E_HK);
    count_hs_kernel<<<(E_HS + 255) / 256, 256, 0, stream>>>(e_hs_src, e_hs_dst, deg, E_HS);
    int nb = (NTOT + 255) / 256; // 438
    scan_block_kernel<<<nb, 256, 0, stream>>>(deg, cur, bsum, NTOT);
    scan2_kernel<<<1, 512, 0, stream>>>(bsum, nb);
    scan_add_kernel<<<nb, 256, 0, stream>>>(cur, bsum, NTOT);
    fill_hk_kernel<<<(E_HK + 255) / 256, 256, 0, stream>>>(e_hk_src, e_hk_dst, cur, adj, E_HK);
    fill_hs_kernel<<<(E_HS + 255) / 256, 256, 0, stream>>>(e_hs_src, e_hs_dst, cur, adj, E_HS);

    // ---- weight conversion ----
    auto split = [&](const float* s, u16* h, u16* l, int n) {
        split_kernel<<<(n / 4 + 255) / 256, 256, 0, stream>>>(s, h, l, n);
    };
    split(Wn, WnH, WnL, 196608);
    split(Wk, WkH, WkL, 32768);
    split(Wst, WsH, WsL, 16384);
    split(W1l, W1lH, W1lL, 262144);
    split(W1r, W1r0H, W1r0L, 65536);
    split(W1r + 2 * 65536, W1r2H, W1r2L, 65536);
    split(W2l, W2lH, W2lL, 131072);
    split(W2r, W2r0H, W2r0L, 32768);
    split(W2r + 2 * 32768, W2r2H, W2r2L, 32768);
    split(DW1, DW1H, DW1L, 65536);
    add2split_kernel<<<(65536 / 4 + 255) / 256, 256, 0, stream>>>(W1r + 65536, W1r + 3 * 65536, SW1H, SW1L, 65536);
    add2split_kernel<<<(32768 / 4 + 255) / 256, 256, 0, stream>>>(W2r + 32768, W2r + 3 * 32768, SW2H, SW2L, 32768);
    add2_kernel<<<1, 256, 0, stream>>>(b1 + 256, b1 + 3 * 256, BS1, 256);
    add2_kernel<<<1, 128, 0, stream>>>(b2 + 128, b2 + 3 * 128, BS2, 128);

    // ---- GEMM wrappers ----
    auto gemmF = [&](const float* A, int lda, const u16* Bh, const u16* Bl, int ldw,
                     const float* bias, u16* Ch, u16* Cl, int ldc,
                     int M, int N, int K, int flags) {
        dim3 g((M + 127) / 128, N / 128);
        gemm_kernel<0, 0, false><<<g, 256, 0, stream>>>(
            A, nullptr, nullptr, nullptr, nullptr, nullptr, nullptr, lda,
            Bh, Bl, ldw, bias, Ch, Cl, ldc, nullptr, nullptr, nullptr, M, N, K, flags);
    };
    auto gemmP = [&](const u16* Ahp, const u16* Alp, int lda, const u16* Bh, const u16* Bl, int ldw,
                     const float* bias, u16* Ch, u16* Cl, int ldc,
                     int M, int N, int K, int flags) {
        dim3 g((M + 127) / 128, N / 128);
        gemm_kernel<1, 0, false><<<g, 256, 0, stream>>>(
            nullptr, Ahp, Alp, nullptr, nullptr, nullptr, nullptr, lda,
            Bh, Bl, ldw, bias, Ch, Cl, ldc, nullptr, nullptr, nullptr, M, N, K, flags);
    };
    auto gemmLP = [&](const u16* Ahp, int lda, const u16* Bh, int ldw,
                      u16* Ch, int ldc, int M, int N, int K) {
        dim3 g((M + 127) / 128, N / 128);
        gemm_kernel<1, 1, true><<<g, 256, 0, stream>>>(
            nullptr, Ahp, nullptr, nullptr, nullptr, nullptr, nullptr, lda,
            Bh, nullptr, ldw, nullptr, Ch, nullptr, ldc, nullptr, nullptr, nullptr, M, N, K, 0);
    };
    auto gemmD = [&](const u16* A1hp, const u16* A1lp, const u16* A2hp, const u16* A2lp,
                     const int* r1, const int* r2,
                     const u16* Bh, const u16* Bl,
                     const float* bias, const float* dw2, const float* db2, float* ov) {
        dim3 g((E_LBL + 127) / 128, 1);
        gemm_kernel<2, 2, false><<<g, 256, 0, stream>>>(
            nullptr, A1hp, A1lp, A2hp, A2lp, r1, r2, 128,
            Bh, Bl, 256, bias, nullptr, nullptr, 0, dw2, db2, ov, E_LBL, 128, 256, 0);
    };

    // ---- input projections ----
    gemmF(x_news, F_NEWS, WnH, WnL, F_NEWS, bn, HNh, HNl, HID, N_NEWS, HID, F_NEWS, FLAG_RELU);
    gemmF(x_kw,   F_KW,   WkH, WkL, F_KW,   bk, HKh, HKl, HID, N_KW,   HID, F_KW,   FLAG_RELU);
    gemmF(x_st,   F_ST,   WsH, WsL, F_ST,   bs, HSh, HSl, HID, N_ST,   HID, F_ST,   FLAG_RELU);

    // ---- layer 1 ----
    gather_mean_kernel<256><<<(N_KW + 3) / 4, 256, 0, stream>>>(HNh, cur + OFFA, deg + OFFA, adj, PAh, PAl, N_KW);
    gemmP(PAh, PAl, HID, W1lH, W1lL, HID, b1, K1h, K1l, HID, N_KW, HID, HID, 0);
    gemmP(HKh, HKl, HID, W1r0H, W1r0L, HID, nullptr, K1h, K1l, HID, N_KW, HID, HID, FLAG_ACC | FLAG_RELU);
    gather_mean_kernel<256><<<(N_ST + 3) / 4, 256, 0, stream>>>(HNh, cur + OFFB, deg + OFFB, adj, PAh, PAl, N_ST);
    gemmP(PAh, PAl, HID, W1lH + 2 * 65536, W1lL + 2 * 65536, HID, b1 + 2 * 256, S1h, S1l, HID, N_ST, HID, HID, 0);
    gemmP(HSh, HSl, HID, W1r2H, W1r2L, HID, nullptr, S1h, S1l, HID, N_ST, HID, HID, FLAG_ACC | FLAG_RELU);
    gemmLP(HKh, HID, W1lH + 1 * 65536, HID, PAh, HID, N_KW, HID, HID);   // PP
    gemmLP(HSh, HID, W1lH + 3 * 65536, HID, PAl, HID, N_ST, HID, HID);   // PP2
    gemmP(HNh, HNl, HID, SW1H, SW1L, HID, BS1, N1h, N1l, HID, N_NEWS, HID, HID, 0);
    fuse_news_kernel<256, true><<<(N_NEWS + 3) / 4, 256, 0, stream>>>(
        PAh, PAl, cur + OFFC, deg + OFFC, cur + OFFD, deg + OFFD, adj, N1h, N1l, N_NEWS);

    // ---- layer 2 ----
    gather_mean_kernel<256><<<(N_KW + 3) / 4, 256, 0, stream>>>(N1h, cur + OFFA, deg + OFFA, adj, PAh, PAl, N_KW);
    gemmP(PAh, PAl, HID, W2lH, W2lL, HID, b2, K2h, K2l, OUTD, N_KW, OUTD, HID, 0);
    gemmP(K1h, K1l, HID, W2r0H, W2r0L, HID, nullptr, K2h, K2l, OUTD, N_KW, OUTD, HID, FLAG_ACC);
    gather_mean_kernel<256><<<(N_ST + 3) / 4, 256, 0, stream>>>(N1h, cur + OFFB, deg + OFFB, adj, PAh, PAl, N_ST);
    gemmP(PAh, PAl, HID, W2lH + 2 * 32768, W2lL + 2 * 32768, HID, b2 + 2 * 128, S2h, S2l, OUTD, N_ST, OUTD, HID, 0);
    gemmP(S1h, S1l, HID, W2r2H, W2r2L, HID, nullptr, S2h, S2l, OUTD, N_ST, OUTD, HID, FLAG_ACC);
    gemmLP(K1h, HID, W2lH + 1 * 32768, HID, PAh, OUTD, N_KW, OUTD, HID);  // PP (n2)
    gemmLP(S1h, HID, W2lH + 3 * 32768, HID, PAl, OUTD, N_ST, OUTD, HID);  // PP2 (n2)
    gemmP(N1h, N1l, HID, SW2H, SW2L, HID, BS2, N2h, N2l, OUTD, N_NEWS, OUTD, HID, 0);
    fuse_news_kernel<128, false><<<(N_NEWS + 7) / 8, 256, 0, stream>>>(
        PAh, PAl, cur + OFFC, deg + OFFC, cur + OFFD, deg + OFFD, adj, N2h, N2l, N_NEWS);

    // ---- fused decoders ----
    gemmD(N2h, N2l, K2h, K2l, l_hk_src, l_hk_dst, DW1H, DW1L, Db1, DW2, Db2, out);
    gemmD(N2h, N2l, S2h, S2l, l_hs_src, l_hs_dst, DW1H + 32768, DW1L + 32768,
          Db1 + 128, DW2 + 128, Db2 + 1, out + E_LBL);
}

// Round 6
// 939.898 us; speedup vs baseline: 11.4470x; 1.1758x over previous
//
#include <hip/hip_runtime.h>
#include <hip/hip_bf16.h>

// ---------------- problem constants ----------------
constexpr int N_NEWS = 50000, N_KW = 10000, N_ST = 2000;
constexpr int F_NEWS = 768, F_KW = 128, F_ST = 64;
constexpr int HID = 256, OUTD = 128;
constexpr int E_HK = 500000, E_HS = 250000, E_LBL = 150000;

// CSR section offsets in the concatenated degree/cursor pools
constexpr int OFFA = 0;                    // e_hk keyed by dst (kw)
constexpr int OFFB = N_KW;                 // e_hs keyed by dst (st)
constexpr int OFFC = N_KW + N_ST;          // e_hk keyed by src (news)
constexpr int OFFD = OFFC + N_NEWS;        // e_hs keyed by src (news)
constexpr int NTOT = OFFD + N_NEWS;        // 112000

enum { FLAG_ACC = 1, FLAG_RELU = 2 };

typedef unsigned short u16;
typedef __attribute__((ext_vector_type(8))) short bf16x8;
typedef __attribute__((ext_vector_type(8))) unsigned short u16x8;
typedef __attribute__((ext_vector_type(4))) float f32x4;

__device__ __forceinline__ u16 f2bf(float x) {
    return __builtin_bit_cast(u16, __float2bfloat16(x));
}
__device__ __forceinline__ float bf2f(u16 h) {
    unsigned u = ((unsigned)h) << 16;
    return __builtin_bit_cast(float, u);
}
__device__ __forceinline__ void split2(float x, u16& h, u16& l) {
    h = f2bf(x);
    l = f2bf(x - bf2f(h));
}

// ---------------- split-bf16 MFMA GEMM, swizzled LDS, register-prefetch pipeline --------
// tile 128x128, BK=32, 4 waves (2x2). 3 MFMA/product (hi*hi+hi*lo+lo*hi); LOWP: 1.
// ASRC: 0 = fp32 A (convert in staging), 1 = plane A, 2 = dual-table plane A (pivot kpiv)
// WMODE: 0 = write hi+lo planes, 1 = hi only, 2 = fused decoder reduce -> outv
template<int ASRC, int WMODE, bool LOWP>
__global__ __launch_bounds__(256) void gemm_kernel(
    const float* __restrict__ Af,
    const u16* __restrict__ A1h, const u16* __restrict__ A1l,
    const u16* __restrict__ A2h, const u16* __restrict__ A2l,
    const int* __restrict__ ridx1, const int* __restrict__ ridx2, int lda, int kpiv,
    const u16* __restrict__ Bhg, const u16* __restrict__ Blg, int ldw,
    const float* __restrict__ bias,
    u16* __restrict__ Chi, u16* __restrict__ Clo, int ldc,
    const float* __restrict__ dw2, const float* __restrict__ db2,
    float* __restrict__ outv,
    int M, int N, int K, int flags)
{
    __shared__ u16 Ah[128 * 32], Bh[128 * 32];
    __shared__ u16 Al[128 * 32], Bl[128 * 32];
    __shared__ float red[128];

    const int tid = threadIdx.x;
    const int bm = blockIdx.x * 128;
    const int bn = blockIdx.y * 128;
    const int l = tid & 63;
    const int w = tid >> 6;
    const int wm = w >> 1, wn = w & 1;
    const int lg = l >> 4, lr = l & 15;

    // ---- hoisted staging pointers (2 passes of 256 threads) ----
    const float* pAf[2];
    const u16 *pA1h[2], *pA1l[2], *pA2h[2], *pA2l[2], *pBh[2], *pBl[2];
    int usw[2];
    #pragma unroll
    for (int p = 0; p < 2; ++p) {
        int g = tid + p * 256;
        int row = g >> 2, c8 = (g & 3) * 8;
        usw[p] = (row * 32 + c8) ^ ((row & 7) << 3);
        int rg = bm + row; if (rg > M - 1) rg = M - 1;
        long br = (long)(bn + row) * ldw + c8;
        pBh[p] = Bhg + br;
        if constexpr (!LOWP) pBl[p] = Blg + br;
        if constexpr (ASRC == 0) {
            long ar = ridx1 ? (long)ridx1[rg] : (long)rg;
            pAf[p] = Af + ar * lda + c8;
        } else if constexpr (ASRC == 1) {
            long ar = ridx1 ? (long)ridx1[rg] : (long)rg;
            pA1h[p] = A1h + ar * lda + c8;
            if constexpr (!LOWP) pA1l[p] = A1l + ar * lda + c8;
        } else {
            long a1 = ridx1 ? (long)ridx1[rg] : (long)rg;
            long a2 = ridx2 ? (long)ridx2[rg] : (long)rg;
            pA1h[p] = A1h + a1 * lda + c8;
            pA1l[p] = A1l + a1 * lda + c8;
            pA2h[p] = A2h + a2 * lda + c8 - kpiv;
            pA2l[p] = A2l + a2 * lda + c8 - kpiv;
        }
    }

    float4 va[2][2];
    u16x8 rah[2], ral[2], rbh[2], rbl[2];

    auto LOAD = [&](int k0) {
        #pragma unroll
        for (int p = 0; p < 2; ++p) {
            if constexpr (ASRC == 0) {
                va[p][0] = ((const float4*)(pAf[p] + k0))[0];
                va[p][1] = ((const float4*)(pAf[p] + k0))[1];
            } else if constexpr (ASRC == 1) {
                rah[p] = *(const u16x8*)(pA1h[p] + k0);
                if constexpr (!LOWP) ral[p] = *(const u16x8*)(pA1l[p] + k0);
            } else {
                const u16* ph = (k0 < kpiv) ? pA1h[p] + k0 : pA2h[p] + k0;
                const u16* pl = (k0 < kpiv) ? pA1l[p] + k0 : pA2l[p] + k0;
                rah[p] = *(const u16x8*)ph;
                ral[p] = *(const u16x8*)pl;
            }
            rbh[p] = *(const u16x8*)(pBh[p] + k0);
            if constexpr (!LOWP) rbl[p] = *(const u16x8*)(pBl[p] + k0);
        }
    };
    auto STORE = [&]() {
        #pragma unroll
        for (int p = 0; p < 2; ++p) {
            if constexpr (ASRC == 0) {
                float vv[8] = {va[p][0].x, va[p][0].y, va[p][0].z, va[p][0].w,
                               va[p][1].x, va[p][1].y, va[p][1].z, va[p][1].w};
                u16x8 h8, l8;
                #pragma unroll
                for (int q = 0; q < 8; ++q) { u16 hh, ll; split2(vv[q], hh, ll); h8[q] = hh; l8[q] = ll; }
                *(u16x8*)&Ah[usw[p]] = h8;
                *(u16x8*)&Al[usw[p]] = l8;
            } else {
                *(u16x8*)&Ah[usw[p]] = rah[p];
                if constexpr (!LOWP) *(u16x8*)&Al[usw[p]] = ral[p];
            }
            *(u16x8*)&Bh[usw[p]] = rbh[p];
            if constexpr (!LOWP) *(u16x8*)&Bl[usw[p]] = rbl[p];
        }
    };

    f32x4 acc[4][4];
    #pragma unroll
    for (int i = 0; i < 4; ++i)
        #pragma unroll
        for (int j = 0; j < 4; ++j) acc[i][j] = (f32x4){0.f, 0.f, 0.f, 0.f};

    LOAD(0);
    for (int k0 = 0; k0 < K; k0 += 32) {
        __syncthreads();            // prev-tile fragment reads done -> LDS reusable
        STORE();
        __syncthreads();            // tile ready
        if (k0 + 32 < K) LOAD(k0 + 32);   // prefetch next tile; latency hides under MFMA

        bf16x8 fah[4], fal[4], fbh[4], fbl[4];
        #pragma unroll
        for (int mt = 0; mt < 4; ++mt) {
            int r = wm * 64 + mt * 16 + lr;
            int us = (r * 32 + lg * 8) ^ ((r & 7) << 3);
            fah[mt] = *(const bf16x8*)&Ah[us];
            if constexpr (!LOWP) fal[mt] = *(const bf16x8*)&Al[us];
        }
        #pragma unroll
        for (int nt = 0; nt < 4; ++nt) {
            int r = wn * 64 + nt * 16 + lr;
            int us = (r * 32 + lg * 8) ^ ((r & 7) << 3);
            fbh[nt] = *(const bf16x8*)&Bh[us];
            if constexpr (!LOWP) fbl[nt] = *(const bf16x8*)&Bl[us];
        }
        #pragma unroll
        for (int mt = 0; mt < 4; ++mt)
            #pragma unroll
            for (int nt = 0; nt < 4; ++nt) {
                acc[mt][nt] = __builtin_amdgcn_mfma_f32_16x16x32_bf16(fah[mt], fbh[nt], acc[mt][nt], 0, 0, 0);
                if constexpr (!LOWP) {
                    acc[mt][nt] = __builtin_amdgcn_mfma_f32_16x16x32_bf16(fah[mt], fbl[nt], acc[mt][nt], 0, 0, 0);
                    acc[mt][nt] = __builtin_amdgcn_mfma_f32_16x16x32_bf16(fal[mt], fbh[nt], acc[mt][nt], 0, 0, 0);
                }
            }
    }

    if constexpr (WMODE == 2) {
        // fused decoder: out[row] = sum_col relu(acc+bias)*dw2[col] + db2
        if (tid < 128) red[tid] = 0.f;
        __syncthreads();
        float bv[4], dwv[4];
        #pragma unroll
        for (int nt = 0; nt < 4; ++nt) {
            int colg = wn * 64 + nt * 16 + lr;
            bv[nt] = bias[colg];
            dwv[nt] = dw2[colg];
        }
        #pragma unroll
        for (int mt = 0; mt < 4; ++mt)
            #pragma unroll
            for (int j = 0; j < 4; ++j) {
                float p = 0.f;
                #pragma unroll
                for (int nt = 0; nt < 4; ++nt)
                    p += fmaxf(acc[mt][nt][j] + bv[nt], 0.f) * dwv[nt];
                p += __shfl_xor(p, 1);
                p += __shfl_xor(p, 2);
                p += __shfl_xor(p, 4);
                p += __shfl_xor(p, 8);
                if (lr == 0) atomicAdd(&red[wm * 64 + mt * 16 + lg * 4 + j], p);
            }
        __syncthreads();
        if (tid < 128) {
            int row = bm + tid;
            if (row < M) outv[row] = red[tid] + db2[0];
        }
    } else {
        float bv[4];
        int col[4];
        #pragma unroll
        for (int nt = 0; nt < 4; ++nt) {
            col[nt] = bn + wn * 64 + nt * 16 + lr;
            bv[nt] = bias ? bias[col[nt]] : 0.f;
        }
        #pragma unroll
        for (int mt = 0; mt < 4; ++mt) {
            int row0 = bm + wm * 64 + mt * 16 + lg * 4;
            #pragma unroll
            for (int j = 0; j < 4; ++j) {
                int row = row0 + j;
                if (row >= M) continue;
                size_t rbase = (size_t)row * ldc;
                #pragma unroll
                for (int nt = 0; nt < 4; ++nt) {
                    size_t off = rbase + col[nt];
                    float v = acc[mt][nt][j];
                    if (flags & FLAG_ACC) v += bf2f(Chi[off]) + bf2f(Clo[off]);
                    v += bv[nt];
                    if (flags & FLAG_RELU) v = fmaxf(v, 0.f);
                    u16 hh, ll; split2(v, hh, ll);
                    Chi[off] = hh;
                    if constexpr (WMODE == 0) Clo[off] = ll;
                }
            }
        }
    }
}

// ---------------- CSR build (merged, sections A|B|C|D) ----------------
__global__ void count_all_kernel(const int* __restrict__ hks, const int* __restrict__ hkd,
                                 const int* __restrict__ hss, const int* __restrict__ hsd,
                                 int* __restrict__ deg)
{
    int e = blockIdx.x * blockDim.x + threadIdx.x;
    if (e < E_HK) {
        atomicAdd(deg + OFFA + hkd[e], 1);
        atomicAdd(deg + OFFC + hks[e], 1);
    } else if (e < E_HK + E_HS) {
        int i = e - E_HK;
        atomicAdd(deg + OFFB + hsd[i], 1);
        atomicAdd(deg + OFFD + hss[i], 1);
    }
}

__global__ void scan_block_kernel(const int* __restrict__ in, int* __restrict__ out,
                                  int* __restrict__ bsum, int n)
{
    __shared__ int tmp[256];
    int i = blockIdx.x * 256 + threadIdx.x;
    int v = (i < n) ? in[i] : 0;
    tmp[threadIdx.x] = v;
    __syncthreads();
    #pragma unroll
    for (int off = 1; off < 256; off <<= 1) {
        int t = (threadIdx.x >= off) ? tmp[threadIdx.x - off] : 0;
        __syncthreads();
        tmp[threadIdx.x] += t;
        __syncthreads();
    }
    if (i < n) out[i] = tmp[threadIdx.x] - v;
    if (threadIdx.x == 255 && bsum) bsum[blockIdx.x] = tmp[255];
}

__global__ void scan2_kernel(int* __restrict__ data, int n) // n <= 512, in-place exclusive
{
    __shared__ int tmp[512];
    int v = (threadIdx.x < n) ? data[threadIdx.x] : 0;
    tmp[threadIdx.x] = v;
    __syncthreads();
    #pragma unroll
    for (int off = 1; off < 512; off <<= 1) {
        int t = (threadIdx.x >= off) ? tmp[threadIdx.x - off] : 0;
        __syncthreads();
        tmp[threadIdx.x] += t;
        __syncthreads();
    }
    if (threadIdx.x < n) data[threadIdx.x] = tmp[threadIdx.x] - v;
}

__global__ void scan_add_kernel(int* __restrict__ out, const int* __restrict__ bsumex, int n)
{
    int i = blockIdx.x * 256 + threadIdx.x;
    if (i < n) out[i] += bsumex[blockIdx.x];
}

__global__ void fill_all_kernel(const int* __restrict__ hks, const int* __restrict__ hkd,
                                const int* __restrict__ hss, const int* __restrict__ hsd,
                                int* __restrict__ cur, u16* __restrict__ adj)
{
    int e = blockIdx.x * blockDim.x + threadIdx.x;
    if (e < E_HK) {
        int s = hks[e], d = hkd[e];
        int p = atomicAdd(cur + OFFA + d, 1); adj[p] = (u16)s;
        int q = atomicAdd(cur + OFFC + s, 1); adj[q] = (u16)d;
    } else if (e < E_HK + E_HS) {
        int i = e - E_HK;
        int s = hss[i], d = hsd[i];
        int p = atomicAdd(cur + OFFB + d, 1); adj[p] = (u16)s;
        int q = atomicAdd(cur + OFFD + s, 1); adj[q] = (u16)d;
    }
}

// ---------------- gather mean (hi-plane read, hi/lo write) ----------------
template <int D>
__global__ void gather_mean_kernel(const u16* __restrict__ Xhi,
                                   const int* __restrict__ cur, const int* __restrict__ deg,
                                   const u16* __restrict__ adj,
                                   u16* __restrict__ Ohi, u16* __restrict__ Olo, int ndst)
{
    constexpr int LANES = D / 4;
    constexpr int RPB = 256 / LANES;
    int r = blockIdx.x * RPB + threadIdx.x / LANES;
    if (r >= ndst) return;
    int lane = threadIdx.x % LANES;
    int end = cur[r];
    int n = deg[r];
    int j = end - n;
    float4 s = {0.f, 0.f, 0.f, 0.f};
    for (; j + 1 < end; j += 2) {
        int s0 = adj[j], s1 = adj[j + 1];
        ushort4 a = *(const ushort4*)(Xhi + (size_t)s0 * D + lane * 4);
        ushort4 b = *(const ushort4*)(Xhi + (size_t)s1 * D + lane * 4);
        s.x += bf2f(a.x) + bf2f(b.x); s.y += bf2f(a.y) + bf2f(b.y);
        s.z += bf2f(a.z) + bf2f(b.z); s.w += bf2f(a.w) + bf2f(b.w);
    }
    if (j < end) {
        ushort4 a = *(const ushort4*)(Xhi + (size_t)adj[j] * D + lane * 4);
        s.x += bf2f(a.x); s.y += bf2f(a.y); s.z += bf2f(a.z); s.w += bf2f(a.w);
    }
    float inv = (n > 0) ? 1.0f / (float)n : 0.f;
    s.x *= inv; s.y *= inv; s.z *= inv; s.w *= inv;
    size_t off = (size_t)r * D + lane * 4;
    ushort4 h, l;
    split2(s.x, h.x, l.x); split2(s.y, h.y, l.y); split2(s.z, h.z, l.z); split2(s.w, h.w, l.w);
    *(ushort4*)(Ohi + off) = h;
    *(ushort4*)(Olo + off) = l;
}

// ---------------- fused news assembly: N += meanC(PP) + meanD(PP2); [relu] ----------------
template <int D, bool RELU>
__global__ void fuse_news_kernel(const u16* __restrict__ PPh, const u16* __restrict__ PP2h,
                                 const int* __restrict__ curC, const int* __restrict__ degC,
                                 const int* __restrict__ curD, const int* __restrict__ degD,
                                 const u16* __restrict__ adj,
                                 u16* __restrict__ Nh, u16* __restrict__ Nl, int ndst)
{
    constexpr int LANES = D / 4;
    constexpr int RPB = 256 / LANES;
    int r = blockIdx.x * RPB + threadIdx.x / LANES;
    if (r >= ndst) return;
    int lane = threadIdx.x % LANES;
    float4 s = {0.f, 0.f, 0.f, 0.f};
    {
        int end = curC[r], n = degC[r];
        float4 a = {0.f, 0.f, 0.f, 0.f};
        for (int j = end - n; j < end; ++j) {
            ushort4 v = *(const ushort4*)(PPh + (size_t)adj[j] * D + lane * 4);
            a.x += bf2f(v.x); a.y += bf2f(v.y); a.z += bf2f(v.z); a.w += bf2f(v.w);
        }
        float inv = (n > 0) ? 1.0f / (float)n : 0.f;
        s.x += a.x * inv; s.y += a.y * inv; s.z += a.z * inv; s.w += a.w * inv;
    }
    {
        int end = curD[r], n = degD[r];
        float4 a = {0.f, 0.f, 0.f, 0.f};
        for (int j = end - n; j < end; ++j) {
            ushort4 v = *(const ushort4*)(PP2h + (size_t)adj[j] * D + lane * 4);
            a.x += bf2f(v.x); a.y += bf2f(v.y); a.z += bf2f(v.z); a.w += bf2f(v.w);
        }
        float inv = (n > 0) ? 1.0f / (float)n : 0.f;
        s.x += a.x * inv; s.y += a.y * inv; s.z += a.z * inv; s.w += a.w * inv;
    }
    size_t off = (size_t)r * D + lane * 4;
    ushort4 h = *(const ushort4*)(Nh + off);
    ushort4 l = *(const ushort4*)(Nl + off);
    s.x += bf2f(h.x) + bf2f(l.x); s.y += bf2f(h.y) + bf2f(l.y);
    s.z += bf2f(h.z) + bf2f(l.z); s.w += bf2f(h.w) + bf2f(l.w);
    if (RELU) {
        s.x = fmaxf(s.x, 0.f); s.y = fmaxf(s.y, 0.f);
        s.z = fmaxf(s.z, 0.f); s.w = fmaxf(s.w, 0.f);
    }
    ushort4 oh, ol;
    split2(s.x, oh.x, ol.x); split2(s.y, oh.y, ol.y); split2(s.z, oh.z, ol.z); split2(s.w, oh.w, ol.w);
    *(ushort4*)(Nh + off) = oh;
    *(ushort4*)(Nl + off) = ol;
}

// ---------------- batched weight split/convert ----------------
#define MAXJOBS 20
struct SplitJobs {
    const float* a[MAXJOBS];
    const float* b[MAXJOBS];     // optional second operand (summed)
    u16* hi[MAXJOBS];
    u16* lo[MAXJOBS];
    int n[MAXJOBS];
    int ncols[MAXJOBS];          // source row width
    int dstride[MAXJOBS];        // dest row stride
    int boff[MAXJOBS + 1];
    int njobs;
};

__global__ void split_all_kernel(SplitJobs J)
{
    int bid = blockIdx.x;
    int j = 0;
    while (j + 1 < J.njobs && bid >= J.boff[j + 1]) ++j;
    int i = (bid - J.boff[j]) * 1024 + threadIdx.x * 4;
    if (i >= J.n[j]) return;
    float4 v = *(const float4*)(J.a[j] + i);
    if (J.b[j]) {
        float4 w = *(const float4*)(J.b[j] + i);
        v.x += w.x; v.y += w.y; v.z += w.z; v.w += w.w;
    }
    int row = i / J.ncols[j], col = i - row * J.ncols[j];
    size_t d = (size_t)row * J.dstride[j] + col;
    ushort4 h, l;
    split2(v.x, h.x, l.x); split2(v.y, h.y, l.y); split2(v.z, h.z, l.z); split2(v.w, h.w, l.w);
    *(ushort4*)(J.hi[j] + d) = h;
    *(ushort4*)(J.lo[j] + d) = l;
}

__global__ void bias_sum_kernel(const float* __restrict__ b1, const float* __restrict__ b2,
                                float* __restrict__ BS1, float* __restrict__ BS2)
{
    int i = blockIdx.x * 256 + threadIdx.x;
    if (i < 256) BS1[i] = b1[256 + i] + b1[768 + i];
    else if (i < 384) { int j = i - 256; BS2[j] = b2[128 + j] + b2[384 + j]; }
}

// ---------------- launch ----------------
extern "C" void kernel_launch(void* const* d_in, const int* in_sizes, int n_in,
                              void* d_out, int out_size, void* d_ws, size_t ws_size,
                              hipStream_t stream)
{
    const float* x_news = (const float*)d_in[0];
    const float* x_kw   = (const float*)d_in[1];
    const float* x_st   = (const float*)d_in[2];
    const float* Wn = (const float*)d_in[3];  const float* bn = (const float*)d_in[4];
    const float* Wk = (const float*)d_in[5];  const float* bk = (const float*)d_in[6];
    const float* Wst = (const float*)d_in[7]; const float* bs = (const float*)d_in[8];
    const float* W1l = (const float*)d_in[9];  const float* b1 = (const float*)d_in[10];
    const float* W1r = (const float*)d_in[11];
    const float* W2l = (const float*)d_in[12]; const float* b2 = (const float*)d_in[13];
    const float* W2r = (const float*)d_in[14];
    const float* DW1 = (const float*)d_in[15]; const float* Db1 = (const float*)d_in[16];
    const float* DW2 = (const float*)d_in[17]; const float* Db2 = (const float*)d_in[18];
    const int* e_hk_src = (const int*)d_in[19];
    const int* e_hk_dst = (const int*)d_in[20];
    const int* e_hs_src = (const int*)d_in[21];
    const int* e_hs_dst = (const int*)d_in[22];
    const int* l_hk_src = (const int*)d_in[23];
    const int* l_hk_dst = (const int*)d_in[24];
    const int* l_hs_src = (const int*)d_in[25];
    const int* l_hs_dst = (const int*)d_in[26];
    float* out = (float*)d_out;

    // ---- workspace layout (bytes, 16B aligned) ----
    char* base = (char*)d_ws;
    auto alloc = [&](size_t bytes) -> char* {
        char* p = base;
        base += (bytes + 15) & ~(size_t)15;
        return p;
    };
    auto aplane = [&](size_t elems) -> u16* { return (u16*)alloc(elems * 2); };

    u16* HNh = aplane((size_t)N_NEWS * HID);  u16* HNl = aplane((size_t)N_NEWS * HID);
    u16* HKh = aplane((size_t)N_KW * HID);    u16* HKl = aplane((size_t)N_KW * HID);
    u16* HSh = aplane((size_t)N_ST * HID);    u16* HSl = aplane((size_t)N_ST * HID);
    u16* K1h = aplane((size_t)N_KW * HID);    u16* K1l = aplane((size_t)N_KW * HID);
    u16* S1h = aplane((size_t)N_ST * HID);    u16* S1l = aplane((size_t)N_ST * HID);
    u16* PAh = aplane((size_t)N_KW * HID);    u16* PAl = aplane((size_t)N_KW * HID);
    u16* N1h = aplane((size_t)N_NEWS * HID);  u16* N1l = aplane((size_t)N_NEWS * HID);
    // weight planes
    u16* WnH = aplane(196608);  u16* WnL = aplane(196608);
    u16* WkH = aplane(32768);   u16* WkL = aplane(32768);
    u16* WsH = aplane(16384);   u16* WsL = aplane(16384);
    u16* CW1KH = aplane(131072); u16* CW1KL = aplane(131072);  // [256][512] W1l0|W1r0
    u16* CW1SH = aplane(131072); u16* CW1SL = aplane(131072);  // [256][512] W1l2|W1r2
    u16* W1l1H = aplane(65536);  u16* W1l1L = aplane(65536);
    u16* W1l3H = aplane(65536);  u16* W1l3L = aplane(65536);
    u16* SW1H = aplane(65536);   u16* SW1L = aplane(65536);    // W1r1+W1r3
    u16* CW2KH = aplane(65536);  u16* CW2KL = aplane(65536);   // [128][512] W2l0|W2r0
    u16* CW2SH = aplane(65536);  u16* CW2SL = aplane(65536);   // [128][512] W2l2|W2r2
    u16* W2l1H = aplane(32768);  u16* W2l1L = aplane(32768);
    u16* W2l3H = aplane(32768);  u16* W2l3L = aplane(32768);
    u16* SW2H = aplane(32768);   u16* SW2L = aplane(32768);    // W2r1+W2r3
    u16* DW1H = aplane(65536);   u16* DW1L = aplane(65536);
    float* BS1 = (float*)alloc(256 * 4);
    float* BS2 = (float*)alloc(128 * 4);
    // int pools
    int* deg = (int*)alloc((size_t)NTOT * 4);
    int* cur = (int*)alloc((size_t)NTOT * 4);
    u16* adj = (u16*)alloc((size_t)2 * (E_HK + E_HS) * 2);
    int* bsum = (int*)alloc(512 * 4);

    // overlays: layer-2 outputs reuse the HN region (dead after layer 1)
    u16* K2h = HNh;
    u16* K2l = K2h + (size_t)N_KW * OUTD;
    u16* N2h = K2l + (size_t)N_KW * OUTD;
    u16* N2l = N2h + (size_t)N_NEWS * OUTD;
    u16* S2h = N2l + (size_t)N_NEWS * OUTD;
    u16* S2l = S2h + (size_t)N_ST * OUTD;

    // ---- CSR build ----
    hipMemsetAsync(deg, 0, (size_t)NTOT * sizeof(int), stream);
    int etot = E_HK + E_HS;
    count_all_kernel<<<(etot + 255) / 256, 256, 0, stream>>>(e_hk_src, e_hk_dst, e_hs_src, e_hs_dst, deg);
    int nb = (NTOT + 255) / 256; // 438
    scan_block_kernel<<<nb, 256, 0, stream>>>(deg, cur, bsum, NTOT);
    scan2_kernel<<<1, 512, 0, stream>>>(bsum, nb);
    scan_add_kernel<<<nb, 256, 0, stream>>>(cur, bsum, NTOT);
    fill_all_kernel<<<(etot + 255) / 256, 256, 0, stream>>>(e_hk_src, e_hk_dst, e_hs_src, e_hs_dst, cur, adj);

    // ---- batched weight conversion ----
    {
        SplitJobs J{};
        int nj = 0, blocks = 0;
        auto job = [&](const float* a, const float* b, u16* hi, u16* lo, int n, int ncols, int dstride) {
            J.a[nj] = a; J.b[nj] = b; J.hi[nj] = hi; J.lo[nj] = lo;
            J.n[nj] = n; J.ncols[nj] = ncols; J.dstride[nj] = dstride;
            J.boff[nj] = blocks;
            blocks += (n / 4 + 255) / 256;
            ++nj;
        };
        job(Wn, nullptr, WnH, WnL, 196608, 196608, 196608);
        job(Wk, nullptr, WkH, WkL, 32768, 32768, 32768);
        job(Wst, nullptr, WsH, WsL, 16384, 16384, 16384);
        job(W1l + 0 * 65536, nullptr, CW1KH, CW1KL, 65536, 256, 512);
        job(W1r + 0 * 65536, nullptr, CW1KH + 256, CW1KL + 256, 65536, 256, 512);
        job(W1l + 2 * 65536, nullptr, CW1SH, CW1SL, 65536, 256, 512);
        job(W1r + 2 * 65536, nullptr, CW1SH + 256, CW1SL + 256, 65536, 256, 512);
        job(W1l + 1 * 65536, nullptr, W1l1H, W1l1L, 65536, 65536, 65536);
        job(W1l + 3 * 65536, nullptr, W1l3H, W1l3L, 65536, 65536, 65536);
        job(W1r + 1 * 65536, W1r + 3 * 65536, SW1H, SW1L, 65536, 65536, 65536);
        job(W2l + 0 * 32768, nullptr, CW2KH, CW2KL, 32768, 256, 512);
        job(W2r + 0 * 32768, nullptr, CW2KH + 256, CW2KL + 256, 32768, 256, 512);
        job(W2l + 2 * 32768, nullptr, CW2SH, CW2SL, 32768, 256, 512);
        job(W2r + 2 * 32768, nullptr, CW2SH + 256, CW2SL + 256, 32768, 256, 512);
        job(W2l + 1 * 32768, nullptr, W2l1H, W2l1L, 32768, 32768, 32768);
        job(W2l + 3 * 32768, nullptr, W2l3H, W2l3L, 32768, 32768, 32768);
        job(W2r + 1 * 32768, W2r + 3 * 32768, SW2H, SW2L, 32768, 32768, 32768);
        job(DW1, nullptr, DW1H, DW1L, 65536, 65536, 65536);
        J.boff[nj] = blocks;
        J.njobs = nj;
        split_all_kernel<<<blocks, 256, 0, stream>>>(J);
    }
    bias_sum_kernel<<<2, 256, 0, stream>>>(b1, b2, BS1, BS2);

    // ---- GEMM wrappers ----
    auto gemmF = [&](const float* A, int lda, const u16* Bh, const u16* Bl, int ldw,
                     const float* bias, u16* Ch, u16* Cl, int ldc,
                     int M, int N, int K, int flags) {
        dim3 g((M + 127) / 128, N / 128);
        gemm_kernel<0, 0, false><<<g, 256, 0, stream>>>(
            A, nullptr, nullptr, nullptr, nullptr, nullptr, nullptr, lda, 0,
            Bh, Bl, ldw, bias, Ch, Cl, ldc, nullptr, nullptr, nullptr, M, N, K, flags);
    };
    auto gemmP = [&](const u16* Ahp, const u16* Alp, int lda, const u16* Bh, const u16* Bl, int ldw,
                     const float* bias, u16* Ch, u16* Cl, int ldc,
                     int M, int N, int K, int flags) {
        dim3 g((M + 127) / 128, N / 128);
        gemm_kernel<1, 0, false><<<g, 256, 0, stream>>>(
            nullptr, Ahp, Alp, nullptr, nullptr, nullptr, nullptr, lda, 0,
            Bh, Bl, ldw, bias, Ch, Cl, ldc, nullptr, nullptr, nullptr, M, N, K, flags);
    };
    auto gemm2 = [&](const u16* A1hp, const u16* A1lp, const u16* A2hp, const u16* A2lp,
                     int lda, int kpiv, const u16* Bh, const u16* Bl, int ldw,
                     const float* bias, u16* Ch, u16* Cl, int ldc,
                     int M, int N, int K, int flags) {
        dim3 g((M + 127) / 128, N / 128);
        gemm_kernel<2, 0, false><<<g, 256, 0, stream>>>(
            nullptr, A1hp, A1lp, A2hp, A2lp, nullptr, nullptr, lda, kpiv,
            Bh, Bl, ldw, bias, Ch, Cl, ldc, nullptr, nullptr, nullptr, M, N, K, flags);
    };
    auto gemmLP = [&](const u16* Ahp, int lda, const u16* Bh, int ldw,
                      u16* Ch, int ldc, int M, int N, int K) {
        dim3 g((M + 127) / 128, N / 128);
        gemm_kernel<1, 1, true><<<g, 256, 0, stream>>>(
            nullptr, Ahp, nullptr, nullptr, nullptr, nullptr, nullptr, lda, 0,
            Bh, nullptr, ldw, nullptr, Ch, nullptr, ldc, nullptr, nullptr, nullptr, M, N, K, 0);
    };
    auto gemmD = [&](const u16* A1hp, const u16* A1lp, const u16* A2hp, const u16* A2lp,
                     const int* r1, const int* r2,
                     const u16* Bh, const u16* Bl,
                     const float* bias, const float* dw2, const float* db2, float* ov) {
        dim3 g((E_LBL + 127) / 128, 1);
        gemm_kernel<2, 2, false><<<g, 256, 0, stream>>>(
            nullptr, A1hp, A1lp, A2hp, A2lp, r1, r2, 128, 128,
            Bh, Bl, 256, bias, nullptr, nullptr, 0, dw2, db2, ov, E_LBL, 128, 256, 0);
    };

    // ---- input projections ----
    gemmF(x_news, F_NEWS, WnH, WnL, F_NEWS, bn, HNh, HNl, HID, N_NEWS, HID, F_NEWS, FLAG_RELU);
    gemmF(x_kw,   F_KW,   WkH, WkL, F_KW,   bk, HKh, HKl, HID, N_KW,   HID, F_KW,   FLAG_RELU);
    gemmF(x_st,   F_ST,   WsH, WsL, F_ST,   bs, HSh, HSl, HID, N_ST,   HID, F_ST,   FLAG_RELU);

    // ---- layer 1 ----
    // k1 = relu([mean_A(hn) | hk] @ [W1l0|W1r0]^T + b1[0])
    gather_mean_kernel<256><<<(N_KW + 3) / 4, 256, 0, stream>>>(HNh, cur + OFFA, deg + OFFA, adj, PAh, PAl, N_KW);
    gemm2(PAh, PAl, HKh, HKl, HID, 256, CW1KH, CW1KL, 512, b1, K1h, K1l, HID, N_KW, HID, 512, FLAG_RELU);
    // s1
    gather_mean_kernel<256><<<(N_ST + 3) / 4, 256, 0, stream>>>(HNh, cur + OFFB, deg + OFFB, adj, PAh, PAl, N_ST);
    gemm2(PAh, PAl, HSh, HSl, HID, 256, CW1SH, CW1SL, 512, b1 + 2 * 256, S1h, S1l, HID, N_ST, HID, 512, FLAG_RELU);
    // n1: project small sources (hi-only), r-term GEMM, fused gather-assembly
    gemmLP(HKh, HID, W1l1H, HID, PAh, HID, N_KW, HID, HID);   // PP
    gemmLP(HSh, HID, W1l3H, HID, PAl, HID, N_ST, HID, HID);   // PP2
    gemmP(HNh, HNl, HID, SW1H, SW1L, HID, BS1, N1h, N1l, HID, N_NEWS, HID, HID, 0);
    fuse_news_kernel<256, true><<<(N_NEWS + 3) / 4, 256, 0, stream>>>(
        PAh, PAl, cur + OFFC, deg + OFFC, cur + OFFD, deg + OFFD, adj, N1h, N1l, N_NEWS);

    // ---- layer 2 ----
    gather_mean_kernel<256><<<(N_KW + 3) / 4, 256, 0, stream>>>(N1h, cur + OFFA, deg + OFFA, adj, PAh, PAl, N_KW);
    gemm2(PAh, PAl, K1h, K1l, HID, 256, CW2KH, CW2KL, 512, b2, K2h, K2l, OUTD, N_KW, OUTD, 512, 0);
    gather_mean_kernel<256><<<(N_ST + 3) / 4, 256, 0, stream>>>(N1h, cur + OFFB, deg + OFFB, adj, PAh, PAl, N_ST);
    gemm2(PAh, PAl, S1h, S1l, HID, 256, CW2SH, CW2SL, 512, b2 + 2 * 128, S2h, S2l, OUTD, N_ST, OUTD, 512, 0);
    gemmLP(K1h, HID, W2l1H, HID, PAh, OUTD, N_KW, OUTD, HID);  // PP (n2)
    gemmLP(S1h, HID, W2l3H, HID, PAl, OUTD, N_ST, OUTD, HID);  // PP2 (n2)
    gemmP(N1h, N1l, HID, SW2H, SW2L, HID, BS2, N2h, N2l, OUTD, N_NEWS, OUTD, HID, 0);
    fuse_news_kernel<128, false><<<(N_NEWS + 7) / 8, 256, 0, stream>>>(
        PAh, PAl, cur + OFFC, deg + OFFC, cur + OFFD, deg + OFFD, adj, N2h, N2l, N_NEWS);

    // ---- fused decoders ----
    gemmD(N2h, N2l, K2h, K2l, l_hk_src, l_hk_dst, DW1H, DW1L, Db1, DW2, Db2, out);
    gemmD(N2h, N2l, S2h, S2l, l_hs_src, l_hs_dst, DW1H + 32768, DW1L + 32768,
          Db1 + 128, DW2 + 128, Db2 + 1, out + E_LBL);
}